// Round 6
// baseline (559.069 us; speedup 1.0000x reference)
//
#include <hip/hip_runtime.h>

#define N_NODES 100000
#define N_EDGES 1600000
#define D 128
#define DE 32
#define SCAN_CHUNK 1024
#define N_CHUNKS ((N_NODES + SCAN_CHUNK - 1) / SCAN_CHUNK)  // 98
#define GBLK 2048
#define CHUNKS4 ((N_NODES + 3) / 4)  // 25000

typedef int v4i __attribute__((ext_vector_type(4)));

// NOTE on eps: reference divides by sqrt(deg_in*deg_out)+1e-10 with both
// degrees >= 1, so the +1e-10 is a 1e-10 relative perturbation — far below
// f32 rounding. We factor w = ew * rsqrt(di) * rsqrt(do).

// ---------------------------------------------------------------------------
// K1: zero deg replicas + cursor (contiguous 5N region).
__global__ __launch_bounds__(256) void init_kernel(int* __restrict__ z) {
  int idx = blockIdx.x * 256 + threadIdx.x;
  if (idx < 5 * N_NODES) z[idx] = 0;
}

// ---------------------------------------------------------------------------
// K2: per-edge: deg_in replica atomic + cursor position atomic. 2 edges/thr.
__global__ __launch_bounds__(256) void pos_kernel(
    const int4* __restrict__ el2, const float2* __restrict__ ew2,
    float* __restrict__ deg4, int* __restrict__ cursor,
    int2* __restrict__ pos2) {
  int i = blockIdx.x * 256 + threadIdx.x;  // edge-pair index
  if (i >= N_EDGES / 2) return;
  int4 e = el2[i];
  float2 w = ew2[i];
  int r = (threadIdx.x & 3) * N_NODES;
  atomicAdd(&deg4[r + e.x], w.x);
  atomicAdd(&deg4[r + e.z], w.y);
  int2 p;
  p.x = atomicAdd(&cursor[e.y], 1);
  p.y = atomicAdd(&cursor[e.w], 1);
  pos2[i] = p;
}

// ---------------------------------------------------------------------------
// K3a: per-1024-chunk exclusive scan of counts(=cursor) -> partial, totals;
// also folds the deg replica reduction into rdi = rsqrt(1 + sum).
__global__ __launch_bounds__(256) void scan1_kernel(
    const int* __restrict__ counts, const float* __restrict__ deg4,
    int* __restrict__ partial, int* __restrict__ blocksum,
    float* __restrict__ rdi) {
  __shared__ int lds[256];
  int t = threadIdx.x;
  int base = blockIdx.x * SCAN_CHUNK + t * 4;
  int c[4];
  int s = 0;
#pragma unroll
  for (int k = 0; k < 4; k++) {
    c[k] = (base + k < N_NODES) ? counts[base + k] : 0;
    s += c[k];
  }
  lds[t] = s;
  __syncthreads();
  for (int off = 1; off < 256; off <<= 1) {
    int tmp = (t >= off) ? lds[t - off] : 0;
    __syncthreads();
    lds[t] += tmp;
    __syncthreads();
  }
  int run = lds[t] - s;
#pragma unroll
  for (int k = 0; k < 4; k++) {
    int v = base + k;
    if (v < N_NODES) {
      partial[v] = run;
      rdi[v] = rsqrtf(1.f + deg4[v] + deg4[N_NODES + v] +
                      deg4[2 * N_NODES + v] + deg4[3 * N_NODES + v]);
    }
    run += c[k];
  }
  if (t == 255) blocksum[blockIdx.x] = lds[255];
}

// ---------------------------------------------------------------------------
// K3b: exclusive scan of the 98 chunk totals.
__global__ __launch_bounds__(128) void scan2_kernel(
    const int* __restrict__ blocksum, int* __restrict__ blockoff) {
  __shared__ int lds[128];
  int t = threadIdx.x;
  int v = (t < N_CHUNKS) ? blocksum[t] : 0;
  lds[t] = v;
  __syncthreads();
  for (int off = 1; off < 128; off <<= 1) {
    int tmp = (t >= off) ? lds[t - off] : 0;
    __syncthreads();
    lds[t] += tmp;
    __syncthreads();
  }
  if (t < N_CHUNKS) blockoff[t] = lds[t] - v;
}

// ---------------------------------------------------------------------------
// K4: place 16B AoS records {src, eid, ew, 0} at start[dst]+pos. No atomics.
__global__ __launch_bounds__(256) void place_kernel(
    const int4* __restrict__ el2, const float2* __restrict__ ew2,
    const int2* __restrict__ pos2, const int* __restrict__ partial,
    const int* __restrict__ blockoff, int4* __restrict__ rec) {
  int i = blockIdx.x * 256 + threadIdx.x;  // edge-pair index
  if (i >= N_EDGES / 2) return;
  int4 e = el2[i];
  float2 w = ew2[i];
  int2 p = pos2[i];
  int4 rA, rB;
  rA.x = e.x; rA.y = 2 * i;     rA.z = __float_as_int(w.x); rA.w = 0;
  rB.x = e.z; rB.y = 2 * i + 1; rB.z = __float_as_int(w.y); rB.w = 0;
  rec[partial[e.y] + blockoff[e.y >> 10] + p.x] = rA;
  rec[partial[e.w] + blockoff[e.w >> 10] + p.y] = rB;
}

// ---------------------------------------------------------------------------
// K5 (fused gather+update): one wave per dst node, grid-stride over chunks.
//  pass1: dsum = sum raw ew -> rdo = rsqrt(1+dsum)
//  pass2: w = ew*rdi[src]*rdo; shfl-broadcast; accumulate sum(w*x[src]) in
//         regs, sum(w*ef) (nt loads — ef has zero reuse, keep L3 for x),
//         sum(w).
//  epilogue: out[v] = accrow + wself*x[v] + g@W_edge^T + wsum*b_edge,
//         W_edge/b_edge in LDS (staged once per block), nt stores.
__global__ __launch_bounds__(256) void gather_kernel(
    const float* __restrict__ x, const float* __restrict__ ef,
    const int* __restrict__ partial, const int* __restrict__ blockoff,
    const int* __restrict__ counts, const int4* __restrict__ rec,
    const float* __restrict__ rdi, const float* __restrict__ W_edge,
    const float* __restrict__ b_edge, float* __restrict__ out) {
  __shared__ __align__(16) float we[128 * 36];
  __shared__ float beS[128];
  int t = threadIdx.x;
#pragma unroll
  for (int i = 0; i < 4; ++i) {  // 1024 float4 / 256 threads
    int f = t + i * 256;
    int r = f >> 3, kq = f & 7;
    *(float4*)&we[r * 36 + 4 * kq] = *(const float4*)&W_edge[r * DE + 4 * kq];
  }
  if (t < 128) beS[t] = b_edge[t];
  __syncthreads();  // the only barrier; loop below has none (wave-uniform)

  int wid = t >> 6, lane = t & 63;
  for (int c = blockIdx.x; c < CHUNKS4; c += GBLK) {
    int v = c * 4 + wid;
    if (v >= N_NODES) continue;  // uniform across the wave
    int start = partial[v] + blockoff[v >> 10];
    int cnt = counts[v];

    // pass 1: raw weighted in-degree of v
    float dsum = 0.f;
    for (int p = lane; p < cnt; p += 64)
      dsum += __int_as_float(rec[start + p].z);
#pragma unroll
    for (int off = 32; off; off >>= 1) dsum += __shfl_xor(dsum, off);
    float rdo = rsqrtf(1.f + dsum);

    float a0 = 0.f, a1 = 0.f, b0 = 0.f, b1 = 0.f, ga = 0.f, wsv = 0.f;
    for (int base = 0; base < cnt; base += 64) {
      int nb = cnt - base;
      if (nb > 64) nb = 64;
      int s_l = 0, e_l = 0;
      float w_l = 0.f;
      if (lane < nb) {
        int4 r = rec[start + base + lane];
        s_l = r.x;
        e_l = r.y;
        w_l = __int_as_float(r.z) * rdi[r.x] * rdo;
        wsv += w_l;
      }
      int i = 0;
      for (; i + 2 <= nb; i += 2) {
        int sA = __shfl(s_l, i), sB = __shfl(s_l, i + 1);
        float wA = __shfl(w_l, i), wB = __shfl(w_l, i + 1);
        int eA = __shfl(e_l, i), eB = __shfl(e_l, i + 1);
        const float* xA = x + (size_t)sA * D;
        const float* xB = x + (size_t)sB * D;
        float xa0 = xA[lane], xa1 = xA[lane + 64];
        float xb0 = xB[lane], xb1 = xB[lane + 64];
        float wE = (lane < 32) ? wA : wB;
        int eE = (lane < 32) ? eA : eB;
        float efv = __builtin_nontemporal_load(&ef[(size_t)eE * DE + (lane & 31)]);
        a0 = fmaf(wA, xa0, a0);
        a1 = fmaf(wA, xa1, a1);
        b0 = fmaf(wB, xb0, b0);
        b1 = fmaf(wB, xb1, b1);
        ga = fmaf(wE, efv, ga);
      }
      if (i < nb) {
        int sA = __shfl(s_l, i);
        float wA = __shfl(w_l, i);
        int eA = __shfl(e_l, i);
        const float* xA = x + (size_t)sA * D;
        a0 = fmaf(wA, xA[lane], a0);
        a1 = fmaf(wA, xA[lane + 64], a1);
        if (lane < DE)
          ga = fmaf(wA, __builtin_nontemporal_load(&ef[(size_t)eA * DE + lane]),
                    ga);
      }
    }
    a0 += b0;
    a1 += b1;
#pragma unroll
    for (int off = 32; off; off >>= 1) wsv += __shfl_xor(wsv, off);
    float gk = ga + __shfl(ga, (lane + 32) & 63);  // full g_k on lanes 0..31

    // epilogue: finish the row in registers
    float wself = rdi[v] * rdo;
    size_t ro = (size_t)v * D;
    float s0 = a0 + wself * x[ro + lane] + wsv * beS[lane];
    float s1 = a1 + wself * x[ro + lane + 64] + wsv * beS[lane + 64];
#pragma unroll
    for (int kq = 0; kq < 8; ++kq) {
      float4 w0 = *(const float4*)&we[lane * 36 + 4 * kq];
      float4 w1 = *(const float4*)&we[(lane + 64) * 36 + 4 * kq];
      float g0 = __shfl(gk, 4 * kq);
      float g1 = __shfl(gk, 4 * kq + 1);
      float g2 = __shfl(gk, 4 * kq + 2);
      float g3 = __shfl(gk, 4 * kq + 3);
      s0 += g0 * w0.x + g1 * w0.y + g2 * w0.z + g3 * w0.w;
      s1 += g0 * w1.x + g1 * w1.y + g2 * w1.z + g3 * w1.w;
    }
    __builtin_nontemporal_store(s0, &out[ro + lane]);
    __builtin_nontemporal_store(s1, &out[ro + lane + 64]);
  }
}

// ---------------------------------------------------------------------------
// K6: in-place per-128-row-tile SGEMM: out = relu(out @ W_lin^T + b_lin).
// BM=128, BN=128, BK=32; 8x8 thread tile split (4+4)x(4+4).
// LDS: stride-32 rows with float4 XOR swizzle (4kq ^ 4*((row>>2)&7)).
__global__ __launch_bounds__(256) void gemm2_kernel(
    const float* __restrict__ W_lin, const float* __restrict__ b_lin,
    float* __restrict__ out) {
  __shared__ __align__(16) float xs[128 * 32];
  __shared__ __align__(16) float wl[128 * 32];
  int t = threadIdx.x;
  int tn = t & 15, tm = t >> 4;
  int m0 = 4 * tm, n0 = 4 * tn;
  int vbase = blockIdx.x * 128;
  float acc[8][8] = {};

  for (int ks = 0; ks < D; ks += 32) {
    __syncthreads();
#pragma unroll
    for (int i = 0; i < 4; ++i) {
      int f = t + i * 256;
      int r = f >> 3, kq = f & 7;
      int sw = (4 * kq) ^ (4 * ((r >> 2) & 7));
      float4 xv = make_float4(0.f, 0.f, 0.f, 0.f);
      if (vbase + r < N_NODES)
        xv = *(const float4*)&out[(size_t)(vbase + r) * D + ks + 4 * kq];
      *(float4*)&xs[r * 32 + sw] = xv;
      *(float4*)&wl[r * 32 + sw] = *(const float4*)&W_lin[r * D + ks + 4 * kq];
    }
    __syncthreads();
#pragma unroll
    for (int kq = 0; kq < 8; ++kq) {
      int sa = (4 * kq) ^ (4 * (tm & 7));
      int sb = (4 * kq) ^ (4 * (tn & 7));
      float4 a[8], b[8];
#pragma unroll
      for (int i = 0; i < 4; ++i) {
        a[i] = *(const float4*)&xs[(m0 + i) * 32 + sa];
        a[4 + i] = *(const float4*)&xs[(m0 + 64 + i) * 32 + sa];
        b[i] = *(const float4*)&wl[(n0 + i) * 32 + sb];
        b[4 + i] = *(const float4*)&wl[(n0 + 64 + i) * 32 + sb];
      }
#pragma unroll
      for (int i = 0; i < 8; ++i)
#pragma unroll
        for (int j = 0; j < 8; ++j) {
          acc[i][j] += a[i].x * b[j].x + a[i].y * b[j].y + a[i].z * b[j].z +
                       a[i].w * b[j].w;
        }
    }
  }

  float bl[8];
#pragma unroll
  for (int j = 0; j < 4; ++j) {
    bl[j] = b_lin[n0 + j];
    bl[4 + j] = b_lin[n0 + 64 + j];
  }
#pragma unroll
  for (int i = 0; i < 8; ++i) {
    int m = vbase + m0 + (i < 4 ? i : 64 + i - 4);
    if (m >= N_NODES) continue;
    float4 o0, o1;
    o0.x = fmaxf(acc[i][0] + bl[0], 0.f);
    o0.y = fmaxf(acc[i][1] + bl[1], 0.f);
    o0.z = fmaxf(acc[i][2] + bl[2], 0.f);
    o0.w = fmaxf(acc[i][3] + bl[3], 0.f);
    o1.x = fmaxf(acc[i][4] + bl[4], 0.f);
    o1.y = fmaxf(acc[i][5] + bl[5], 0.f);
    o1.z = fmaxf(acc[i][6] + bl[6], 0.f);
    o1.w = fmaxf(acc[i][7] + bl[7], 0.f);
    *(float4*)&out[(size_t)m * D + n0] = o0;
    *(float4*)&out[(size_t)m * D + n0 + 64] = o1;
  }
}

// ---------------------------------------------------------------------------
extern "C" void kernel_launch(void* const* d_in, const int* in_sizes, int n_in,
                              void* d_out, int out_size, void* d_ws,
                              size_t ws_size, hipStream_t stream) {
  const float* x      = (const float*)d_in[0];
  const int*   el     = (const int*)d_in[1];
  const float* ew     = (const float*)d_in[2];
  const float* ef     = (const float*)d_in[3];
  const float* W_lin  = (const float*)d_in[4];
  const float* b_lin  = (const float*)d_in[5];
  const float* W_edge = (const float*)d_in[6];
  const float* b_edge = (const float*)d_in[7];

  float* acc = (float*)d_out;  // gather writes full update rows; gemm2 in place

  // workspace layout (~37 MB), rec first for 16B alignment
  int4* rec      = (int4*)d_ws;                         // E x 16B
  int*  pos      = (int*)(rec + N_EDGES);               // E
  float* deg4    = (float*)(pos + N_EDGES);             // 4N (zeroed w/ cursor)
  int*  cursor   = (int*)(deg4 + 4 * N_NODES);          // N (== counts after K2)
  int*  partial  = cursor + N_NODES;                    // N
  int*  blocksum = partial + N_NODES;                   // 128
  int*  blockoff = blocksum + 128;                      // 128
  float* rdi     = (float*)(blockoff + 128);            // N

  hipLaunchKernelGGL(init_kernel, dim3((5 * N_NODES + 255) / 256), dim3(256),
                     0, stream, (int*)deg4);
  hipLaunchKernelGGL(pos_kernel, dim3((N_EDGES / 2 + 255) / 256), dim3(256), 0,
                     stream, (const int4*)el, (const float2*)ew, deg4, cursor,
                     (int2*)pos);
  hipLaunchKernelGGL(scan1_kernel, dim3(N_CHUNKS), dim3(256), 0, stream,
                     cursor, deg4, partial, blocksum, rdi);
  hipLaunchKernelGGL(scan2_kernel, dim3(1), dim3(128), 0, stream, blocksum,
                     blockoff);
  hipLaunchKernelGGL(place_kernel, dim3((N_EDGES / 2 + 255) / 256), dim3(256),
                     0, stream, (const int4*)el, (const float2*)ew,
                     (const int2*)pos, partial, blockoff, rec);
  hipLaunchKernelGGL(gather_kernel, dim3(GBLK), dim3(256), 0, stream, x, ef,
                     partial, blockoff, cursor, rec, rdi, W_edge, b_edge, acc);
  hipLaunchKernelGGL(gemm2_kernel, dim3((N_NODES + 127) / 128), dim3(256), 0,
                     stream, W_lin, b_lin, acc);
}

// Round 7
// 549.076 us; speedup vs baseline: 1.0182x; 1.0182x over previous
//
#include <hip/hip_runtime.h>

#define N_NODES 100000
#define N_EDGES 1600000
#define D 128
#define DE 32
#define SCAN_CHUNK 1024
#define N_CHUNKS ((N_NODES + SCAN_CHUNK - 1) / SCAN_CHUNK)  // 98

// NOTE on eps: reference divides by sqrt(deg_in*deg_out)+1e-10 with both
// degrees >= 1, so the +1e-10 is a 1e-10 relative perturbation — far below
// f32 rounding. We factor w = ew * rsqrt(di) * rsqrt(do).

// ---------------------------------------------------------------------------
// K1: zero deg replicas + cursor (contiguous 5N region).
__global__ __launch_bounds__(256) void init_kernel(int* __restrict__ z) {
  int idx = blockIdx.x * 256 + threadIdx.x;
  if (idx < 5 * N_NODES) z[idx] = 0;
}

// ---------------------------------------------------------------------------
// K2: per-edge cursor position atomic ONLY (1.6M atomics). 2 edges/thread.
__global__ __launch_bounds__(256) void pos_kernel(
    const int4* __restrict__ el2, int* __restrict__ cursor,
    int2* __restrict__ pos2) {
  int i = blockIdx.x * 256 + threadIdx.x;  // edge-pair index
  if (i >= N_EDGES / 2) return;
  int4 e = el2[i];
  int2 p;
  p.x = atomicAdd(&cursor[e.y], 1);
  p.y = atomicAdd(&cursor[e.w], 1);
  pos2[i] = p;
}

// ---------------------------------------------------------------------------
// K3a: per-1024-chunk exclusive scan of counts(=cursor) -> partial, totals.
__global__ __launch_bounds__(256) void scan1_kernel(
    const int* __restrict__ counts, int* __restrict__ partial,
    int* __restrict__ blocksum) {
  __shared__ int lds[256];
  int t = threadIdx.x;
  int base = blockIdx.x * SCAN_CHUNK + t * 4;
  int c[4];
  int s = 0;
#pragma unroll
  for (int k = 0; k < 4; k++) {
    c[k] = (base + k < N_NODES) ? counts[base + k] : 0;
    s += c[k];
  }
  lds[t] = s;
  __syncthreads();
  for (int off = 1; off < 256; off <<= 1) {
    int tmp = (t >= off) ? lds[t - off] : 0;
    __syncthreads();
    lds[t] += tmp;
    __syncthreads();
  }
  int run = lds[t] - s;
#pragma unroll
  for (int k = 0; k < 4; k++) {
    int v = base + k;
    if (v < N_NODES) partial[v] = run;
    run += c[k];
  }
  if (t == 255) blocksum[blockIdx.x] = lds[255];
}

// ---------------------------------------------------------------------------
// K3b: exclusive scan of the 98 chunk totals.
__global__ __launch_bounds__(128) void scan2_kernel(
    const int* __restrict__ blocksum, int* __restrict__ blockoff) {
  __shared__ int lds[128];
  int t = threadIdx.x;
  int v = (t < N_CHUNKS) ? blocksum[t] : 0;
  lds[t] = v;
  __syncthreads();
  for (int off = 1; off < 128; off <<= 1) {
    int tmp = (t >= off) ? lds[t - off] : 0;
    __syncthreads();
    lds[t] += tmp;
    __syncthreads();
  }
  if (t < N_CHUNKS) blockoff[t] = lds[t] - v;
}

// ---------------------------------------------------------------------------
// K4: place 16B AoS records {src, eid, ew, 0} at start[dst]+pos, and absorb
// the deg_in replica atomics (1.6M) here — this kernel was BW-light.
__global__ __launch_bounds__(256) void place_kernel(
    const int4* __restrict__ el2, const float2* __restrict__ ew2,
    const int2* __restrict__ pos2, const int* __restrict__ partial,
    const int* __restrict__ blockoff, float* __restrict__ deg4,
    int4* __restrict__ rec) {
  int i = blockIdx.x * 256 + threadIdx.x;  // edge-pair index
  if (i >= N_EDGES / 2) return;
  int4 e = el2[i];
  float2 w = ew2[i];
  int2 p = pos2[i];
  int r0 = (threadIdx.x & 3) * N_NODES;
  atomicAdd(&deg4[r0 + e.x], w.x);
  atomicAdd(&deg4[r0 + e.z], w.y);
  int4 rA, rB;
  rA.x = e.x; rA.y = 2 * i;     rA.z = __float_as_int(w.x); rA.w = 0;
  rB.x = e.z; rB.y = 2 * i + 1; rB.z = __float_as_int(w.y); rB.w = 0;
  rec[partial[e.y] + blockoff[e.y >> 10] + p.x] = rA;
  rec[partial[e.w] + blockoff[e.w >> 10] + p.y] = rB;
}

// ---------------------------------------------------------------------------
// K5: finalize rdi = rsqrt(1 + sum of 4 deg replicas).
__global__ __launch_bounds__(256) void rdi_kernel(
    const float* __restrict__ deg4, float* __restrict__ rdi) {
  int v = blockIdx.x * 256 + threadIdx.x;
  if (v >= N_NODES) return;
  rdi[v] = rsqrtf(1.f + deg4[v] + deg4[N_NODES + v] + deg4[2 * N_NODES + v] +
                  deg4[3 * N_NODES + v]);
}

// ---------------------------------------------------------------------------
// K6: edge-feature gather — streams ef exactly once, NO x access.
// One wave per dst node: pass1 Sum(raw ew) -> rdo; pass2 accumulate
// g[v] = Sum(w*ef[eid]) (2 edges/iter in half-waves) and wsum = Sum(w).
__global__ __launch_bounds__(256) void gather_ef_kernel(
    const float* __restrict__ ef, const int* __restrict__ partial,
    const int* __restrict__ blockoff, const int* __restrict__ counts,
    const int4* __restrict__ rec, const float* __restrict__ rdi,
    float* __restrict__ g, float* __restrict__ wsum,
    float* __restrict__ rdo_arr) {
  int wid = threadIdx.x >> 6, lane = threadIdx.x & 63;
  int v = blockIdx.x * 4 + wid;
  if (v >= N_NODES) return;
  int start = partial[v] + blockoff[v >> 10];
  int cnt = counts[v];

  // pass 1: raw weighted in-degree of v -> rdo
  float dsum = 0.f;
  for (int p = lane; p < cnt; p += 64)
    dsum += __int_as_float(rec[start + p].z);
#pragma unroll
  for (int off = 32; off; off >>= 1) dsum += __shfl_xor(dsum, off);
  float rdo = rsqrtf(1.f + dsum);

  float ga = 0.f, wsv = 0.f;
  for (int base = 0; base < cnt; base += 64) {
    int nb = cnt - base;
    if (nb > 64) nb = 64;
    int e_l = 0;
    float w_l = 0.f;
    if (lane < nb) {
      int4 r = rec[start + base + lane];
      e_l = r.y;
      w_l = __int_as_float(r.z) * rdi[r.x] * rdo;
      wsv += w_l;
    }
    int i = 0;
    for (; i + 2 <= nb; i += 2) {
      int sel = (lane < 32) ? i : i + 1;
      int eE = __shfl(e_l, sel);
      float wE = __shfl(w_l, sel);
      ga = fmaf(wE, ef[(size_t)eE * DE + (lane & 31)], ga);
    }
    if (i < nb) {
      int eA = __shfl(e_l, i);
      float wA = __shfl(w_l, i);
      if (lane < DE) ga = fmaf(wA, ef[(size_t)eA * DE + lane], ga);
    }
  }
#pragma unroll
  for (int off = 32; off; off >>= 1) wsv += __shfl_xor(wsv, off);
  float gk = ga + __shfl(ga, (lane + 32) & 63);  // full g_k on lanes 0..31
  if (lane < DE) g[v * DE + lane] = gk;
  if (lane == 0) {
    wsum[v] = wsv;
    rdo_arr[v] = rdo;
  }
}

// ---------------------------------------------------------------------------
// K7: x gather + fused row epilogue — NO ef access, so x's 51MB hot set
// owns the L3. One wave per dst node, 2 edges/iter:
//   row = Sum(w*x[src]) + wself*x[v] + g[v]@W_edge^T + wsum*b_edge
// W_edge/b_edge staged in LDS once per block.
__global__ __launch_bounds__(256) void gather_x_kernel(
    const float* __restrict__ x, const int* __restrict__ partial,
    const int* __restrict__ blockoff, const int* __restrict__ counts,
    const int4* __restrict__ rec, const float* __restrict__ rdi,
    const float* __restrict__ g, const float* __restrict__ wsum,
    const float* __restrict__ rdo_arr, const float* __restrict__ W_edge,
    const float* __restrict__ b_edge, float* __restrict__ out) {
  __shared__ __align__(16) float we[128 * 36];
  __shared__ float beS[128];
  int t = threadIdx.x;
#pragma unroll
  for (int i = 0; i < 4; ++i) {  // 1024 float4 / 256 threads
    int f = t + i * 256;
    int r = f >> 3, kq = f & 7;
    *(float4*)&we[r * 36 + 4 * kq] = *(const float4*)&W_edge[r * DE + 4 * kq];
  }
  if (t < 128) beS[t] = b_edge[t];
  __syncthreads();

  int wid = t >> 6, lane = t & 63;
  int v = blockIdx.x * 4 + wid;
  if (v >= N_NODES) return;
  int start = partial[v] + blockoff[v >> 10];
  int cnt = counts[v];
  float rdo = rdo_arr[v];

  float a0 = 0.f, a1 = 0.f, b0 = 0.f, b1 = 0.f;
  for (int base = 0; base < cnt; base += 64) {
    int nb = cnt - base;
    if (nb > 64) nb = 64;
    int s_l = 0;
    float w_l = 0.f;
    if (lane < nb) {
      int4 r = rec[start + base + lane];
      s_l = r.x;
      w_l = __int_as_float(r.z) * rdi[r.x] * rdo;
    }
    int i = 0;
    for (; i + 2 <= nb; i += 2) {
      int sA = __shfl(s_l, i), sB = __shfl(s_l, i + 1);
      float wA = __shfl(w_l, i), wB = __shfl(w_l, i + 1);
      const float* xA = x + (size_t)sA * D;
      const float* xB = x + (size_t)sB * D;
      a0 = fmaf(wA, xA[lane], a0);
      a1 = fmaf(wA, xA[lane + 64], a1);
      b0 = fmaf(wB, xB[lane], b0);
      b1 = fmaf(wB, xB[lane + 64], b1);
    }
    if (i < nb) {
      int sA = __shfl(s_l, i);
      float wA = __shfl(w_l, i);
      const float* xA = x + (size_t)sA * D;
      a0 = fmaf(wA, xA[lane], a0);
      a1 = fmaf(wA, xA[lane + 64], a1);
    }
  }
  a0 += b0;
  a1 += b1;

  // epilogue: finish the row in registers
  float wsv = wsum[v];
  float gk = g[v * DE + (lane & 31)];
  float wself = rdi[v] * rdo;
  size_t ro = (size_t)v * D;
  float s0 = a0 + wself * x[ro + lane] + wsv * beS[lane];
  float s1 = a1 + wself * x[ro + lane + 64] + wsv * beS[lane + 64];
#pragma unroll
  for (int kq = 0; kq < 8; ++kq) {
    float4 w0 = *(const float4*)&we[lane * 36 + 4 * kq];
    float4 w1 = *(const float4*)&we[(lane + 64) * 36 + 4 * kq];
    float g0 = __shfl(gk, 4 * kq);
    float g1 = __shfl(gk, 4 * kq + 1);
    float g2 = __shfl(gk, 4 * kq + 2);
    float g3 = __shfl(gk, 4 * kq + 3);
    s0 += g0 * w0.x + g1 * w0.y + g2 * w0.z + g3 * w0.w;
    s1 += g0 * w1.x + g1 * w1.y + g2 * w1.z + g3 * w1.w;
  }
  out[ro + lane] = s0;
  out[ro + lane + 64] = s1;
}

// ---------------------------------------------------------------------------
// K8: in-place per-128-row-tile SGEMM: out = relu(out @ W_lin^T + b_lin).
// BM=128, BN=128, BK=32; 8x8 thread tile split (4+4)x(4+4).
// LDS: stride-32 rows with float4 XOR swizzle (4kq ^ 4*((row>>2)&7)).
__global__ __launch_bounds__(256) void gemm2_kernel(
    const float* __restrict__ W_lin, const float* __restrict__ b_lin,
    float* __restrict__ out) {
  __shared__ __align__(16) float xs[128 * 32];
  __shared__ __align__(16) float wl[128 * 32];
  int t = threadIdx.x;
  int tn = t & 15, tm = t >> 4;
  int m0 = 4 * tm, n0 = 4 * tn;
  int vbase = blockIdx.x * 128;
  float acc[8][8] = {};

  for (int ks = 0; ks < D; ks += 32) {
    __syncthreads();
#pragma unroll
    for (int i = 0; i < 4; ++i) {
      int f = t + i * 256;
      int r = f >> 3, kq = f & 7;
      int sw = (4 * kq) ^ (4 * ((r >> 2) & 7));
      float4 xv = make_float4(0.f, 0.f, 0.f, 0.f);
      if (vbase + r < N_NODES)
        xv = *(const float4*)&out[(size_t)(vbase + r) * D + ks + 4 * kq];
      *(float4*)&xs[r * 32 + sw] = xv;
      *(float4*)&wl[r * 32 + sw] = *(const float4*)&W_lin[r * D + ks + 4 * kq];
    }
    __syncthreads();
#pragma unroll
    for (int kq = 0; kq < 8; ++kq) {
      int sa = (4 * kq) ^ (4 * (tm & 7));
      int sb = (4 * kq) ^ (4 * (tn & 7));
      float4 a[8], b[8];
#pragma unroll
      for (int i = 0; i < 4; ++i) {
        a[i] = *(const float4*)&xs[(m0 + i) * 32 + sa];
        a[4 + i] = *(const float4*)&xs[(m0 + 64 + i) * 32 + sa];
        b[i] = *(const float4*)&wl[(n0 + i) * 32 + sb];
        b[4 + i] = *(const float4*)&wl[(n0 + 64 + i) * 32 + sb];
      }
#pragma unroll
      for (int i = 0; i < 8; ++i)
#pragma unroll
        for (int j = 0; j < 8; ++j) {
          acc[i][j] += a[i].x * b[j].x + a[i].y * b[j].y + a[i].z * b[j].z +
                       a[i].w * b[j].w;
        }
    }
  }

  float bl[8];
#pragma unroll
  for (int j = 0; j < 4; ++j) {
    bl[j] = b_lin[n0 + j];
    bl[4 + j] = b_lin[n0 + 64 + j];
  }
#pragma unroll
  for (int i = 0; i < 8; ++i) {
    int m = vbase + m0 + (i < 4 ? i : 64 + i - 4);
    if (m >= N_NODES) continue;
    float4 o0, o1;
    o0.x = fmaxf(acc[i][0] + bl[0], 0.f);
    o0.y = fmaxf(acc[i][1] + bl[1], 0.f);
    o0.z = fmaxf(acc[i][2] + bl[2], 0.f);
    o0.w = fmaxf(acc[i][3] + bl[3], 0.f);
    o1.x = fmaxf(acc[i][4] + bl[4], 0.f);
    o1.y = fmaxf(acc[i][5] + bl[5], 0.f);
    o1.z = fmaxf(acc[i][6] + bl[6], 0.f);
    o1.w = fmaxf(acc[i][7] + bl[7], 0.f);
    *(float4*)&out[(size_t)m * D + n0] = o0;
    *(float4*)&out[(size_t)m * D + n0 + 64] = o1;
  }
}

// ---------------------------------------------------------------------------
extern "C" void kernel_launch(void* const* d_in, const int* in_sizes, int n_in,
                              void* d_out, int out_size, void* d_ws,
                              size_t ws_size, hipStream_t stream) {
  const float* x      = (const float*)d_in[0];
  const int*   el     = (const int*)d_in[1];
  const float* ew     = (const float*)d_in[2];
  const float* ef     = (const float*)d_in[3];
  const float* W_lin  = (const float*)d_in[4];
  const float* b_lin  = (const float*)d_in[5];
  const float* W_edge = (const float*)d_in[6];
  const float* b_edge = (const float*)d_in[7];

  float* outp = (float*)d_out;  // gather_x writes full rows; gemm2 in place

  // workspace layout (~41 MB), rec first for 16B alignment
  int4* rec      = (int4*)d_ws;                         // E x 16B
  int*  pos      = (int*)(rec + N_EDGES);               // E
  float* deg4    = (float*)(pos + N_EDGES);             // 4N (zeroed w/ cursor)
  int*  cursor   = (int*)(deg4 + 4 * N_NODES);          // N (== counts after K2)
  int*  partial  = cursor + N_NODES;                    // N
  int*  blocksum = partial + N_NODES;                   // 128
  int*  blockoff = blocksum + 128;                      // 128
  float* rdi     = (float*)(blockoff + 128);            // N
  float* rdo     = rdi + N_NODES;                       // N
  float* wsum    = rdo + N_NODES;                       // N
  float* g       = wsum + N_NODES;                      // N*32

  hipLaunchKernelGGL(init_kernel, dim3((5 * N_NODES + 255) / 256), dim3(256),
                     0, stream, (int*)deg4);
  hipLaunchKernelGGL(pos_kernel, dim3((N_EDGES / 2 + 255) / 256), dim3(256), 0,
                     stream, (const int4*)el, cursor, (int2*)pos);
  hipLaunchKernelGGL(scan1_kernel, dim3(N_CHUNKS), dim3(256), 0, stream,
                     cursor, partial, blocksum);
  hipLaunchKernelGGL(scan2_kernel, dim3(1), dim3(128), 0, stream, blocksum,
                     blockoff);
  hipLaunchKernelGGL(place_kernel, dim3((N_EDGES / 2 + 255) / 256), dim3(256),
                     0, stream, (const int4*)el, (const float2*)ew,
                     (const int2*)pos, partial, blockoff, deg4, rec);
  hipLaunchKernelGGL(rdi_kernel, dim3((N_NODES + 255) / 256), dim3(256), 0,
                     stream, deg4, rdi);
  hipLaunchKernelGGL(gather_ef_kernel, dim3((N_NODES + 3) / 4), dim3(256), 0,
                     stream, ef, partial, blockoff, cursor, rec, rdi, g, wsum,
                     rdo);
  hipLaunchKernelGGL(gather_x_kernel, dim3((N_NODES + 3) / 4), dim3(256), 0,
                     stream, x, partial, blockoff, cursor, rec, rdi, g, wsum,
                     rdo, W_edge, b_edge, outp);
  hipLaunchKernelGGL(gemm2_kernel, dim3((N_NODES + 127) / 128), dim3(256), 0,
                     stream, W_lin, b_lin, outp);
}

// Round 8
// 489.151 us; speedup vs baseline: 1.1429x; 1.1225x over previous
//
#include <hip/hip_runtime.h>

#define N_NODES 100000
#define N_EDGES 1600000
#define D 128
#define DE 32
#define SCAN_CHUNK 1024
#define N_CHUNKS ((N_NODES + SCAN_CHUNK - 1) / SCAN_CHUNK)  // 98

// NOTE on eps: reference divides by sqrt(deg_in*deg_out)+1e-10 with both
// degrees >= 1, so the +1e-10 is a 1e-10 relative perturbation — far below
// f32 rounding. We factor w = ew * rsqrt(di) * rsqrt(do).

// ---------------------------------------------------------------------------
// K1: zero deg replicas + cursor (contiguous 5N region).
__global__ __launch_bounds__(256) void init_kernel(int* __restrict__ z) {
  int idx = blockIdx.x * 256 + threadIdx.x;
  if (idx < 5 * N_NODES) z[idx] = 0;
}

// ---------------------------------------------------------------------------
// K2: per-edge cursor position atomic ONLY (1.6M atomics). 2 edges/thread.
__global__ __launch_bounds__(256) void pos_kernel(
    const int4* __restrict__ el2, int* __restrict__ cursor,
    int2* __restrict__ pos2) {
  int i = blockIdx.x * 256 + threadIdx.x;  // edge-pair index
  if (i >= N_EDGES / 2) return;
  int4 e = el2[i];
  int2 p;
  p.x = atomicAdd(&cursor[e.y], 1);
  p.y = atomicAdd(&cursor[e.w], 1);
  pos2[i] = p;
}

// ---------------------------------------------------------------------------
// K3a: per-1024-chunk exclusive scan of counts(=cursor) -> partial, totals.
__global__ __launch_bounds__(256) void scan1_kernel(
    const int* __restrict__ counts, int* __restrict__ partial,
    int* __restrict__ blocksum) {
  __shared__ int lds[256];
  int t = threadIdx.x;
  int base = blockIdx.x * SCAN_CHUNK + t * 4;
  int c[4];
  int s = 0;
#pragma unroll
  for (int k = 0; k < 4; k++) {
    c[k] = (base + k < N_NODES) ? counts[base + k] : 0;
    s += c[k];
  }
  lds[t] = s;
  __syncthreads();
  for (int off = 1; off < 256; off <<= 1) {
    int tmp = (t >= off) ? lds[t - off] : 0;
    __syncthreads();
    lds[t] += tmp;
    __syncthreads();
  }
  int run = lds[t] - s;
#pragma unroll
  for (int k = 0; k < 4; k++) {
    int v = base + k;
    if (v < N_NODES) partial[v] = run;
    run += c[k];
  }
  if (t == 255) blocksum[blockIdx.x] = lds[255];
}

// ---------------------------------------------------------------------------
// K3b: exclusive scan of the 98 chunk totals.
__global__ __launch_bounds__(128) void scan2_kernel(
    const int* __restrict__ blocksum, int* __restrict__ blockoff) {
  __shared__ int lds[128];
  int t = threadIdx.x;
  int v = (t < N_CHUNKS) ? blocksum[t] : 0;
  lds[t] = v;
  __syncthreads();
  for (int off = 1; off < 128; off <<= 1) {
    int tmp = (t >= off) ? lds[t - off] : 0;
    __syncthreads();
    lds[t] += tmp;
    __syncthreads();
  }
  if (t < N_CHUNKS) blockoff[t] = lds[t] - v;
}

// ---------------------------------------------------------------------------
// K4: place 16B AoS records {src, eid, ew, 0} at start[dst]+pos, and absorb
// the deg_in replica atomics (1.6M) here — this kernel was BW-light.
__global__ __launch_bounds__(256) void place_kernel(
    const int4* __restrict__ el2, const float2* __restrict__ ew2,
    const int2* __restrict__ pos2, const int* __restrict__ partial,
    const int* __restrict__ blockoff, float* __restrict__ deg4,
    int4* __restrict__ rec) {
  int i = blockIdx.x * 256 + threadIdx.x;  // edge-pair index
  if (i >= N_EDGES / 2) return;
  int4 e = el2[i];
  float2 w = ew2[i];
  int2 p = pos2[i];
  int r0 = (threadIdx.x & 3) * N_NODES;
  atomicAdd(&deg4[r0 + e.x], w.x);
  atomicAdd(&deg4[r0 + e.z], w.y);
  int4 rA, rB;
  rA.x = e.x; rA.y = 2 * i;     rA.z = __float_as_int(w.x); rA.w = 0;
  rB.x = e.z; rB.y = 2 * i + 1; rB.z = __float_as_int(w.y); rB.w = 0;
  rec[partial[e.y] + blockoff[e.y >> 10] + p.x] = rA;
  rec[partial[e.w] + blockoff[e.w >> 10] + p.y] = rB;
}

// ---------------------------------------------------------------------------
// K5: finalize rdi = rsqrt(1 + sum of 4 deg replicas).
__global__ __launch_bounds__(256) void rdi_kernel(
    const float* __restrict__ deg4, float* __restrict__ rdi) {
  int v = blockIdx.x * 256 + threadIdx.x;
  if (v >= N_NODES) return;
  rdi[v] = rsqrtf(1.f + deg4[v] + deg4[N_NODES + v] + deg4[2 * N_NODES + v] +
                  deg4[3 * N_NODES + v]);
}

// ---------------------------------------------------------------------------
// K6: edge-feature gather — streams ef exactly once, NO x access.
__global__ __launch_bounds__(256) void gather_ef_kernel(
    const float* __restrict__ ef, const int* __restrict__ partial,
    const int* __restrict__ blockoff, const int* __restrict__ counts,
    const int4* __restrict__ rec, const float* __restrict__ rdi,
    float* __restrict__ g, float* __restrict__ wsum,
    float* __restrict__ rdo_arr) {
  int wid = threadIdx.x >> 6, lane = threadIdx.x & 63;
  int v = blockIdx.x * 4 + wid;
  if (v >= N_NODES) return;
  int start = partial[v] + blockoff[v >> 10];
  int cnt = counts[v];

  // pass 1: raw weighted in-degree of v -> rdo
  float dsum = 0.f;
  for (int p = lane; p < cnt; p += 64)
    dsum += __int_as_float(rec[start + p].z);
#pragma unroll
  for (int off = 32; off; off >>= 1) dsum += __shfl_xor(dsum, off);
  float rdo = rsqrtf(1.f + dsum);

  float ga = 0.f, wsv = 0.f;
  for (int base = 0; base < cnt; base += 64) {
    int nb = cnt - base;
    if (nb > 64) nb = 64;
    int e_l = 0;
    float w_l = 0.f;
    if (lane < nb) {
      int4 r = rec[start + base + lane];
      e_l = r.y;
      w_l = __int_as_float(r.z) * rdi[r.x] * rdo;
      wsv += w_l;
    }
    int i = 0;
    for (; i + 2 <= nb; i += 2) {
      int sel = (lane < 32) ? i : i + 1;
      int eE = __shfl(e_l, sel);
      float wE = __shfl(w_l, sel);
      ga = fmaf(wE, ef[(size_t)eE * DE + (lane & 31)], ga);
    }
    if (i < nb) {
      int eA = __shfl(e_l, i);
      float wA = __shfl(w_l, i);
      if (lane < DE) ga = fmaf(wA, ef[(size_t)eA * DE + lane], ga);
    }
  }
#pragma unroll
  for (int off = 32; off; off >>= 1) wsv += __shfl_xor(wsv, off);
  float gk = ga + __shfl(ga, (lane + 32) & 63);  // full g_k on lanes 0..31
  if (lane < DE) g[v * DE + lane] = gk;
  if (lane == 0) {
    wsum[v] = wsv;
    rdo_arr[v] = rdo;
  }
}

// ---------------------------------------------------------------------------
// K7: x gather + fused row epilogue — NO ef access, so x's 51MB hot set
// owns the L3.
__global__ __launch_bounds__(256) void gather_x_kernel(
    const float* __restrict__ x, const int* __restrict__ partial,
    const int* __restrict__ blockoff, const int* __restrict__ counts,
    const int4* __restrict__ rec, const float* __restrict__ rdi,
    const float* __restrict__ g, const float* __restrict__ wsum,
    const float* __restrict__ rdo_arr, const float* __restrict__ W_edge,
    const float* __restrict__ b_edge, float* __restrict__ out) {
  __shared__ __align__(16) float we[128 * 36];
  __shared__ float beS[128];
  int t = threadIdx.x;
#pragma unroll
  for (int i = 0; i < 4; ++i) {  // 1024 float4 / 256 threads
    int f = t + i * 256;
    int r = f >> 3, kq = f & 7;
    *(float4*)&we[r * 36 + 4 * kq] = *(const float4*)&W_edge[r * DE + 4 * kq];
  }
  if (t < 128) beS[t] = b_edge[t];
  __syncthreads();

  int wid = t >> 6, lane = t & 63;
  int v = blockIdx.x * 4 + wid;
  if (v >= N_NODES) return;
  int start = partial[v] + blockoff[v >> 10];
  int cnt = counts[v];
  float rdo = rdo_arr[v];

  float a0 = 0.f, a1 = 0.f, b0 = 0.f, b1 = 0.f;
  for (int base = 0; base < cnt; base += 64) {
    int nb = cnt - base;
    if (nb > 64) nb = 64;
    int s_l = 0;
    float w_l = 0.f;
    if (lane < nb) {
      int4 r = rec[start + base + lane];
      s_l = r.x;
      w_l = __int_as_float(r.z) * rdi[r.x] * rdo;
    }
    int i = 0;
    for (; i + 2 <= nb; i += 2) {
      int sA = __shfl(s_l, i), sB = __shfl(s_l, i + 1);
      float wA = __shfl(w_l, i), wB = __shfl(w_l, i + 1);
      const float* xA = x + (size_t)sA * D;
      const float* xB = x + (size_t)sB * D;
      a0 = fmaf(wA, xA[lane], a0);
      a1 = fmaf(wA, xA[lane + 64], a1);
      b0 = fmaf(wB, xB[lane], b0);
      b1 = fmaf(wB, xB[lane + 64], b1);
    }
    if (i < nb) {
      int sA = __shfl(s_l, i);
      float wA = __shfl(w_l, i);
      const float* xA = x + (size_t)sA * D;
      a0 = fmaf(wA, xA[lane], a0);
      a1 = fmaf(wA, xA[lane + 64], a1);
    }
  }
  a0 += b0;
  a1 += b1;

  // epilogue: finish the row in registers
  float wsv = wsum[v];
  float gk = g[v * DE + (lane & 31)];
  float wself = rdi[v] * rdo;
  size_t ro = (size_t)v * D;
  float s0 = a0 + wself * x[ro + lane] + wsv * beS[lane];
  float s1 = a1 + wself * x[ro + lane + 64] + wsv * beS[lane + 64];
#pragma unroll
  for (int kq = 0; kq < 8; ++kq) {
    float4 w0 = *(const float4*)&we[lane * 36 + 4 * kq];
    float4 w1 = *(const float4*)&we[(lane + 64) * 36 + 4 * kq];
    float g0 = __shfl(gk, 4 * kq);
    float g1 = __shfl(gk, 4 * kq + 1);
    float g2 = __shfl(gk, 4 * kq + 2);
    float g3 = __shfl(gk, 4 * kq + 3);
    s0 += g0 * w0.x + g1 * w0.y + g2 * w0.z + g3 * w0.w;
    s1 += g0 * w1.x + g1 * w1.y + g2 * w1.z + g3 * w1.w;
  }
  out[ro + lane] = s0;
  out[ro + lane + 64] = s1;
}

// ---------------------------------------------------------------------------
// K8: in-place per-128-row-tile SGEMM: out = relu(out @ W_lin^T + b_lin).
// BM=128, BN=128, BK=32; 8x8 thread tile split (4+4)x(4+4).
// Register discipline: __launch_bounds__(256,3) caps VGPR ~170 (3 waves/EU),
// kq-loop kept rolled (#pragma unroll 1) so only ONE generation of fragments
// is live, and b-fragments load one-at-a-time inside the j-loop
// (live set = 64 acc + 32 a + 4 b ~ 110 VGPR). R7 failure mode: compiler
// unrolled kq x8, kept a[8]+b[8] per iter live -> 256 VGPR, 8.8% occupancy.
__global__ __launch_bounds__(256, 3) void gemm2_kernel(
    const float* __restrict__ W_lin, const float* __restrict__ b_lin,
    float* __restrict__ out) {
  __shared__ __align__(16) float xs[128 * 32];
  __shared__ __align__(16) float wl[128 * 32];
  int t = threadIdx.x;
  int tn = t & 15, tm = t >> 4;
  int m0 = 4 * tm, n0 = 4 * tn;
  int vbase = blockIdx.x * 128;
  float acc[8][8] = {};

  for (int ks = 0; ks < D; ks += 32) {
    __syncthreads();
#pragma unroll
    for (int i = 0; i < 4; ++i) {
      int f = t + i * 256;
      int r = f >> 3, kq = f & 7;
      int sw = (4 * kq) ^ (4 * ((r >> 2) & 7));
      float4 xv = make_float4(0.f, 0.f, 0.f, 0.f);
      if (vbase + r < N_NODES)
        xv = *(const float4*)&out[(size_t)(vbase + r) * D + ks + 4 * kq];
      *(float4*)&xs[r * 32 + sw] = xv;
      *(float4*)&wl[r * 32 + sw] = *(const float4*)&W_lin[r * D + ks + 4 * kq];
    }
    __syncthreads();
#pragma unroll 1
    for (int kq = 0; kq < 8; ++kq) {
      int sa = (4 * kq) ^ (4 * (tm & 7));
      int sb = (4 * kq) ^ (4 * (tn & 7));
      float4 a[8];
#pragma unroll
      for (int i = 0; i < 4; ++i) {
        a[i] = *(const float4*)&xs[(m0 + i) * 32 + sa];
        a[4 + i] = *(const float4*)&xs[(m0 + 64 + i) * 32 + sa];
      }
#pragma unroll
      for (int j = 0; j < 8; ++j) {
        int rj = (j < 4) ? (n0 + j) : (n0 + 60 + j);
        float4 b = *(const float4*)&wl[rj * 32 + sb];
#pragma unroll
        for (int i = 0; i < 8; ++i) {
          acc[i][j] += a[i].x * b.x + a[i].y * b.y + a[i].z * b.z +
                       a[i].w * b.w;
        }
      }
    }
  }

  float bl[8];
#pragma unroll
  for (int j = 0; j < 4; ++j) {
    bl[j] = b_lin[n0 + j];
    bl[4 + j] = b_lin[n0 + 64 + j];
  }
#pragma unroll
  for (int i = 0; i < 8; ++i) {
    int m = vbase + m0 + (i < 4 ? i : 64 + i - 4);
    if (m >= N_NODES) continue;
    float4 o0, o1;
    o0.x = fmaxf(acc[i][0] + bl[0], 0.f);
    o0.y = fmaxf(acc[i][1] + bl[1], 0.f);
    o0.z = fmaxf(acc[i][2] + bl[2], 0.f);
    o0.w = fmaxf(acc[i][3] + bl[3], 0.f);
    o1.x = fmaxf(acc[i][4] + bl[4], 0.f);
    o1.y = fmaxf(acc[i][5] + bl[5], 0.f);
    o1.z = fmaxf(acc[i][6] + bl[6], 0.f);
    o1.w = fmaxf(acc[i][7] + bl[7], 0.f);
    *(float4*)&out[(size_t)m * D + n0] = o0;
    *(float4*)&out[(size_t)m * D + n0 + 64] = o1;
  }
}

// ---------------------------------------------------------------------------
extern "C" void kernel_launch(void* const* d_in, const int* in_sizes, int n_in,
                              void* d_out, int out_size, void* d_ws,
                              size_t ws_size, hipStream_t stream) {
  const float* x      = (const float*)d_in[0];
  const int*   el     = (const int*)d_in[1];
  const float* ew     = (const float*)d_in[2];
  const float* ef     = (const float*)d_in[3];
  const float* W_lin  = (const float*)d_in[4];
  const float* b_lin  = (const float*)d_in[5];
  const float* W_edge = (const float*)d_in[6];
  const float* b_edge = (const float*)d_in[7];

  float* outp = (float*)d_out;  // gather_x writes full rows; gemm2 in place

  // workspace layout (~41 MB), rec first for 16B alignment
  int4* rec      = (int4*)d_ws;                         // E x 16B
  int*  pos      = (int*)(rec + N_EDGES);               // E
  float* deg4    = (float*)(pos + N_EDGES);             // 4N (zeroed w/ cursor)
  int*  cursor   = (int*)(deg4 + 4 * N_NODES);          // N (== counts after K2)
  int*  partial  = cursor + N_NODES;                    // N
  int*  blocksum = partial + N_NODES;                   // 128
  int*  blockoff = blocksum + 128;                      // 128
  float* rdi     = (float*)(blockoff + 128);            // N
  float* rdo     = rdi + N_NODES;                       // N
  float* wsum    = rdo + N_NODES;                       // N
  float* g       = wsum + N_NODES;                      // N*32

  hipLaunchKernelGGL(init_kernel, dim3((5 * N_NODES + 255) / 256), dim3(256),
                     0, stream, (int*)deg4);
  hipLaunchKernelGGL(pos_kernel, dim3((N_EDGES / 2 + 255) / 256), dim3(256), 0,
                     stream, (const int4*)el, cursor, (int2*)pos);
  hipLaunchKernelGGL(scan1_kernel, dim3(N_CHUNKS), dim3(256), 0, stream,
                     cursor, partial, blocksum);
  hipLaunchKernelGGL(scan2_kernel, dim3(1), dim3(128), 0, stream, blocksum,
                     blockoff);
  hipLaunchKernelGGL(place_kernel, dim3((N_EDGES / 2 + 255) / 256), dim3(256),
                     0, stream, (const int4*)el, (const float2*)ew,
                     (const int2*)pos, partial, blockoff, deg4, rec);
  hipLaunchKernelGGL(rdi_kernel, dim3((N_NODES + 255) / 256), dim3(256), 0,
                     stream, deg4, rdi);
  hipLaunchKernelGGL(gather_ef_kernel, dim3((N_NODES + 3) / 4), dim3(256), 0,
                     stream, ef, partial, blockoff, cursor, rec, rdi, g, wsum,
                     rdo);
  hipLaunchKernelGGL(gather_x_kernel, dim3((N_NODES + 3) / 4), dim3(256), 0,
                     stream, x, partial, blockoff, cursor, rec, rdi, g, wsum,
                     rdo, W_edge, b_edge, outp);
  hipLaunchKernelGGL(gemm2_kernel, dim3((N_NODES + 127) / 128), dim3(256), 0,
                     stream, W_lin, b_lin, outp);
}

// Round 9
// 454.528 us; speedup vs baseline: 1.2300x; 1.0762x over previous
//
#include <hip/hip_runtime.h>

#define N_NODES 100000
#define N_EDGES 1600000
#define D 128
#define DE 32
#define SCAN_CHUNK 1024
#define N_CHUNKS ((N_NODES + SCAN_CHUNK - 1) / SCAN_CHUNK)  // 98

// NOTE on eps: reference divides by sqrt(deg_in*deg_out)+1e-10 with both
// degrees >= 1, so the +1e-10 is a 1e-10 relative perturbation — far below
// f32 rounding. We factor w = ew * rsqrt(di) * rsqrt(do).
//
// NOTE on bf16 gather (R9): neighbor-sum reads bf16(x) (RNE) with f32
// accumulation. Added output error ~0.002-0.004 absmax vs 0.019 threshold.

__device__ inline float bfu(ushort u) {
  return __uint_as_float((unsigned)u << 16);
}
__device__ inline unsigned pk_bf2(float lo, float hi) {
  unsigned a = __float_as_uint(lo), b = __float_as_uint(hi);
  a = (a + 0x7FFFu + ((a >> 16) & 1)) >> 16;           // RNE
  b = (b + 0x7FFFu + ((b >> 16) & 1)) >> 16;
  return a | (b << 16);
}

// ---------------------------------------------------------------------------
// K1: zero deg replicas + cursor (contiguous 5N region).
__global__ __launch_bounds__(256) void init_kernel(int* __restrict__ z) {
  int idx = blockIdx.x * 256 + threadIdx.x;
  if (idx < 5 * N_NODES) z[idx] = 0;
}

// ---------------------------------------------------------------------------
// K2: per-edge cursor position atomic ONLY (1.6M atomics). 2 edges/thread.
__global__ __launch_bounds__(256) void pos_kernel(
    const int4* __restrict__ el2, int* __restrict__ cursor,
    int2* __restrict__ pos2) {
  int i = blockIdx.x * 256 + threadIdx.x;  // edge-pair index
  if (i >= N_EDGES / 2) return;
  int4 e = el2[i];
  int2 p;
  p.x = atomicAdd(&cursor[e.y], 1);
  p.y = atomicAdd(&cursor[e.w], 1);
  pos2[i] = p;
}

// ---------------------------------------------------------------------------
// K3a: per-1024-chunk exclusive scan of counts(=cursor) -> partial, totals.
__global__ __launch_bounds__(256) void scan1_kernel(
    const int* __restrict__ counts, int* __restrict__ partial,
    int* __restrict__ blocksum) {
  __shared__ int lds[256];
  int t = threadIdx.x;
  int base = blockIdx.x * SCAN_CHUNK + t * 4;
  int c[4];
  int s = 0;
#pragma unroll
  for (int k = 0; k < 4; k++) {
    c[k] = (base + k < N_NODES) ? counts[base + k] : 0;
    s += c[k];
  }
  lds[t] = s;
  __syncthreads();
  for (int off = 1; off < 256; off <<= 1) {
    int tmp = (t >= off) ? lds[t - off] : 0;
    __syncthreads();
    lds[t] += tmp;
    __syncthreads();
  }
  int run = lds[t] - s;
#pragma unroll
  for (int k = 0; k < 4; k++) {
    int v = base + k;
    if (v < N_NODES) partial[v] = run;
    run += c[k];
  }
  if (t == 255) blocksum[blockIdx.x] = lds[255];
}

// ---------------------------------------------------------------------------
// K3b: exclusive scan of the 98 chunk totals.
__global__ __launch_bounds__(128) void scan2_kernel(
    const int* __restrict__ blocksum, int* __restrict__ blockoff) {
  __shared__ int lds[128];
  int t = threadIdx.x;
  int v = (t < N_CHUNKS) ? blocksum[t] : 0;
  lds[t] = v;
  __syncthreads();
  for (int off = 1; off < 128; off <<= 1) {
    int tmp = (t >= off) ? lds[t - off] : 0;
    __syncthreads();
    lds[t] += tmp;
    __syncthreads();
  }
  if (t < N_CHUNKS) blockoff[t] = lds[t] - v;
}

// ---------------------------------------------------------------------------
// K4: place 16B AoS records {src, eid, ew, 0} at start[dst]+pos + deg_in
// replica atomics.
__global__ __launch_bounds__(256) void place_kernel(
    const int4* __restrict__ el2, const float2* __restrict__ ew2,
    const int2* __restrict__ pos2, const int* __restrict__ partial,
    const int* __restrict__ blockoff, float* __restrict__ deg4,
    int4* __restrict__ rec) {
  int i = blockIdx.x * 256 + threadIdx.x;  // edge-pair index
  if (i >= N_EDGES / 2) return;
  int4 e = el2[i];
  float2 w = ew2[i];
  int2 p = pos2[i];
  int r0 = (threadIdx.x & 3) * N_NODES;
  atomicAdd(&deg4[r0 + e.x], w.x);
  atomicAdd(&deg4[r0 + e.z], w.y);
  int4 rA, rB;
  rA.x = e.x; rA.y = 2 * i;     rA.z = __float_as_int(w.x); rA.w = 0;
  rB.x = e.z; rB.y = 2 * i + 1; rB.z = __float_as_int(w.y); rB.w = 0;
  rec[partial[e.y] + blockoff[e.y >> 10] + p.x] = rA;
  rec[partial[e.w] + blockoff[e.w >> 10] + p.y] = rB;
}

// ---------------------------------------------------------------------------
// K5: finalize rdi = rsqrt(1 + sum of 4 deg replicas).
__global__ __launch_bounds__(256) void rdi_kernel(
    const float* __restrict__ deg4, float* __restrict__ rdi) {
  int v = blockIdx.x * 256 + threadIdx.x;
  if (v >= N_NODES) return;
  rdi[v] = rsqrtf(1.f + deg4[v] + deg4[N_NODES + v] + deg4[2 * N_NODES + v] +
                  deg4[3 * N_NODES + v]);
}

// ---------------------------------------------------------------------------
// K6: slim record pass: recSW[i] = {src, ew*rdi[src]} (8B/edge) so the hot
// x-gather loop carries no random rdi lookup and half the record bytes.
__global__ __launch_bounds__(256) void wpre_kernel(
    const int4* __restrict__ rec, const float* __restrict__ rdi,
    int2* __restrict__ recSW) {
  int i = blockIdx.x * 256 + threadIdx.x;
  if (i >= N_EDGES) return;
  int4 r = rec[i];
  float w = __int_as_float(r.z) * rdi[r.x];
  recSW[i] = make_int2(r.x, __float_as_int(w));
}

// ---------------------------------------------------------------------------
// K7: xh = bf16(x) table (RNE), 8 elems/thread. Written over the rec region
// (dead after gather_ef).
__global__ __launch_bounds__(256) void xh_kernel(
    const float4* __restrict__ x4, uint4* __restrict__ xh4) {
  int i = blockIdx.x * 256 + threadIdx.x;
  if (i >= N_NODES * D / 8) return;
  float4 f0 = x4[2 * i], f1 = x4[2 * i + 1];
  uint4 o;
  o.x = pk_bf2(f0.x, f0.y);
  o.y = pk_bf2(f0.z, f0.w);
  o.z = pk_bf2(f1.x, f1.y);
  o.w = pk_bf2(f1.z, f1.w);
  xh4[i] = o;
}

// ---------------------------------------------------------------------------
// K8: edge-feature gather — streams ef exactly once, NO x access.
// 4 edges/iter (2 rows in flight per lane via half-wave split).
__global__ __launch_bounds__(256) void gather_ef_kernel(
    const float* __restrict__ ef, const int* __restrict__ partial,
    const int* __restrict__ blockoff, const int* __restrict__ counts,
    const int4* __restrict__ rec, const float* __restrict__ rdi,
    float* __restrict__ g, float* __restrict__ wsum,
    float* __restrict__ rdo_arr) {
  int wid = threadIdx.x >> 6, lane = threadIdx.x & 63;
  int v = blockIdx.x * 4 + wid;
  if (v >= N_NODES) return;
  int start = partial[v] + blockoff[v >> 10];
  int cnt = counts[v];

  // pass 1: raw weighted in-degree of v -> rdo
  float dsum = 0.f;
  for (int p = lane; p < cnt; p += 64)
    dsum += __int_as_float(rec[start + p].z);
#pragma unroll
  for (int off = 32; off; off >>= 1) dsum += __shfl_xor(dsum, off);
  float rdo = rsqrtf(1.f + dsum);

  float ga = 0.f, gb = 0.f, wsv = 0.f;
  for (int base = 0; base < cnt; base += 64) {
    int nb = cnt - base;
    if (nb > 64) nb = 64;
    int e_l = 0;
    float w_l = 0.f;
    if (lane < nb) {
      int4 r = rec[start + base + lane];
      e_l = r.y;
      w_l = __int_as_float(r.z) * rdi[r.x] * rdo;
      wsv += w_l;
    }
    int i = 0;
    for (; i + 4 <= nb; i += 4) {
      int selA = i + (lane >> 5);
      int selB = i + 2 + (lane >> 5);
      int eA = __shfl(e_l, selA);
      float wA = __shfl(w_l, selA);
      int eB = __shfl(e_l, selB);
      float wB = __shfl(w_l, selB);
      ga = fmaf(wA, ef[(size_t)eA * DE + (lane & 31)], ga);
      gb = fmaf(wB, ef[(size_t)eB * DE + (lane & 31)], gb);
    }
    for (; i + 2 <= nb; i += 2) {
      int sel = i + (lane >> 5);
      int eE = __shfl(e_l, sel);
      float wE = __shfl(w_l, sel);
      ga = fmaf(wE, ef[(size_t)eE * DE + (lane & 31)], ga);
    }
    if (i < nb) {
      int eA = __shfl(e_l, i);
      float wA = __shfl(w_l, i);
      if (lane < DE) ga = fmaf(wA, ef[(size_t)eA * DE + lane], ga);
    }
  }
  ga += gb;
#pragma unroll
  for (int off = 32; off; off >>= 1) wsv += __shfl_xor(wsv, off);
  float gk = ga + __shfl(ga, (lane + 32) & 63);  // full g_k on lanes 0..31
  if (lane < DE) g[v * DE + lane] = gk;
  if (lane == 0) {
    wsum[v] = wsv;
    rdo_arr[v] = rdo;
  }
}

// ---------------------------------------------------------------------------
// K9-fast: bf16 x gather + fused row epilogue. 8B records, 256B/row demanded
// (half of f32), 4 edges/iter (8 row-loads in flight), f32 accumulation.
__global__ __launch_bounds__(256) void gather_x_fast_kernel(
    const ushort* __restrict__ xh, const int* __restrict__ partial,
    const int* __restrict__ blockoff, const int* __restrict__ counts,
    const int2* __restrict__ recSW, const float* __restrict__ rdi,
    const float* __restrict__ g, const float* __restrict__ wsum,
    const float* __restrict__ rdo_arr, const float* __restrict__ W_edge,
    const float* __restrict__ b_edge, float* __restrict__ out) {
  __shared__ __align__(16) float we[128 * 36];
  __shared__ float beS[128];
  int t = threadIdx.x;
#pragma unroll
  for (int i = 0; i < 4; ++i) {
    int f = t + i * 256;
    int r = f >> 3, kq = f & 7;
    *(float4*)&we[r * 36 + 4 * kq] = *(const float4*)&W_edge[r * DE + 4 * kq];
  }
  if (t < 128) beS[t] = b_edge[t];
  __syncthreads();

  int wid = t >> 6, lane = t & 63;
  int v = blockIdx.x * 4 + wid;
  if (v >= N_NODES) return;
  int start = partial[v] + blockoff[v >> 10];
  int cnt = counts[v];
  float rdo = rdo_arr[v];

  float A0 = 0.f, A1 = 0.f, B0 = 0.f, B1 = 0.f;
  float C0 = 0.f, C1 = 0.f, E0 = 0.f, E1 = 0.f;
  for (int base = 0; base < cnt; base += 64) {
    int nb = cnt - base;
    if (nb > 64) nb = 64;
    int2 r = make_int2(0, 0);
    if (lane < nb) r = recSW[start + base + lane];
    int s_l = r.x;
    float w_l = __int_as_float(r.y) * rdo;
    int i = 0;
    for (; i + 4 <= nb; i += 4) {
      int s0 = __shfl(s_l, i), s1 = __shfl(s_l, i + 1);
      int s2 = __shfl(s_l, i + 2), s3 = __shfl(s_l, i + 3);
      float w0 = __shfl(w_l, i), w1 = __shfl(w_l, i + 1);
      float w2 = __shfl(w_l, i + 2), w3 = __shfl(w_l, i + 3);
      const ushort* p0 = xh + (size_t)s0 * D;
      const ushort* p1 = xh + (size_t)s1 * D;
      const ushort* p2 = xh + (size_t)s2 * D;
      const ushort* p3 = xh + (size_t)s3 * D;
      float x00 = bfu(p0[lane]), x01 = bfu(p0[lane + 64]);
      float x10 = bfu(p1[lane]), x11 = bfu(p1[lane + 64]);
      float x20 = bfu(p2[lane]), x21 = bfu(p2[lane + 64]);
      float x30 = bfu(p3[lane]), x31 = bfu(p3[lane + 64]);
      A0 = fmaf(w0, x00, A0); A1 = fmaf(w0, x01, A1);
      B0 = fmaf(w1, x10, B0); B1 = fmaf(w1, x11, B1);
      C0 = fmaf(w2, x20, C0); C1 = fmaf(w2, x21, C1);
      E0 = fmaf(w3, x30, E0); E1 = fmaf(w3, x31, E1);
    }
    for (; i < nb; ++i) {
      int s0 = __shfl(s_l, i);
      float w0 = __shfl(w_l, i);
      const ushort* p0 = xh + (size_t)s0 * D;
      A0 = fmaf(w0, bfu(p0[lane]), A0);
      A1 = fmaf(w0, bfu(p0[lane + 64]), A1);
    }
  }
  float a0 = (A0 + B0) + (C0 + E0);
  float a1 = (A1 + B1) + (C1 + E1);

  // epilogue: finish the row in registers
  float wsv = wsum[v];
  float gk = g[v * DE + (lane & 31)];
  float wself = rdi[v] * rdo;
  size_t ro = (size_t)v * D;
  const ushort* pv = xh + ro;
  float s0 = a0 + wself * bfu(pv[lane]) + wsv * beS[lane];
  float s1 = a1 + wself * bfu(pv[lane + 64]) + wsv * beS[lane + 64];
#pragma unroll
  for (int kq = 0; kq < 8; ++kq) {
    float4 w0 = *(const float4*)&we[lane * 36 + 4 * kq];
    float4 w1 = *(const float4*)&we[(lane + 64) * 36 + 4 * kq];
    float g0 = __shfl(gk, 4 * kq);
    float g1 = __shfl(gk, 4 * kq + 1);
    float g2 = __shfl(gk, 4 * kq + 2);
    float g3 = __shfl(gk, 4 * kq + 3);
    s0 += g0 * w0.x + g1 * w0.y + g2 * w0.z + g3 * w0.w;
    s1 += g0 * w1.x + g1 * w1.y + g2 * w1.z + g3 * w1.w;
  }
  out[ro + lane] = s0;
  out[ro + lane + 64] = s1;
}

// ---------------------------------------------------------------------------
// K9-safe: R8's f32 gather (fallback when ws_size can't hold recSW).
__global__ __launch_bounds__(256) void gather_x_safe_kernel(
    const float* __restrict__ x, const int* __restrict__ partial,
    const int* __restrict__ blockoff, const int* __restrict__ counts,
    const int4* __restrict__ rec, const float* __restrict__ rdi,
    const float* __restrict__ g, const float* __restrict__ wsum,
    const float* __restrict__ rdo_arr, const float* __restrict__ W_edge,
    const float* __restrict__ b_edge, float* __restrict__ out) {
  __shared__ __align__(16) float we[128 * 36];
  __shared__ float beS[128];
  int t = threadIdx.x;
#pragma unroll
  for (int i = 0; i < 4; ++i) {
    int f = t + i * 256;
    int r = f >> 3, kq = f & 7;
    *(float4*)&we[r * 36 + 4 * kq] = *(const float4*)&W_edge[r * DE + 4 * kq];
  }
  if (t < 128) beS[t] = b_edge[t];
  __syncthreads();

  int wid = t >> 6, lane = t & 63;
  int v = blockIdx.x * 4 + wid;
  if (v >= N_NODES) return;
  int start = partial[v] + blockoff[v >> 10];
  int cnt = counts[v];
  float rdo = rdo_arr[v];

  float a0 = 0.f, a1 = 0.f, b0 = 0.f, b1 = 0.f;
  for (int base = 0; base < cnt; base += 64) {
    int nb = cnt - base;
    if (nb > 64) nb = 64;
    int s_l = 0;
    float w_l = 0.f;
    if (lane < nb) {
      int4 r = rec[start + base + lane];
      s_l = r.x;
      w_l = __int_as_float(r.z) * rdi[r.x] * rdo;
    }
    int i = 0;
    for (; i + 2 <= nb; i += 2) {
      int sA = __shfl(s_l, i), sB = __shfl(s_l, i + 1);
      float wA = __shfl(w_l, i), wB = __shfl(w_l, i + 1);
      const float* xA = x + (size_t)sA * D;
      const float* xB = x + (size_t)sB * D;
      a0 = fmaf(wA, xA[lane], a0);
      a1 = fmaf(wA, xA[lane + 64], a1);
      b0 = fmaf(wB, xB[lane], b0);
      b1 = fmaf(wB, xB[lane + 64], b1);
    }
    if (i < nb) {
      int sA = __shfl(s_l, i);
      float wA = __shfl(w_l, i);
      const float* xA = x + (size_t)sA * D;
      a0 = fmaf(wA, xA[lane], a0);
      a1 = fmaf(wA, xA[lane + 64], a1);
    }
  }
  a0 += b0;
  a1 += b1;

  float wsv = wsum[v];
  float gk = g[v * DE + (lane & 31)];
  float wself = rdi[v] * rdo;
  size_t ro = (size_t)v * D;
  float s0 = a0 + wself * x[ro + lane] + wsv * beS[lane];
  float s1 = a1 + wself * x[ro + lane + 64] + wsv * beS[lane + 64];
#pragma unroll
  for (int kq = 0; kq < 8; ++kq) {
    float4 w0 = *(const float4*)&we[lane * 36 + 4 * kq];
    float4 w1 = *(const float4*)&we[(lane + 64) * 36 + 4 * kq];
    float g0 = __shfl(gk, 4 * kq);
    float g1 = __shfl(gk, 4 * kq + 1);
    float g2 = __shfl(gk, 4 * kq + 2);
    float g3 = __shfl(gk, 4 * kq + 3);
    s0 += g0 * w0.x + g1 * w0.y + g2 * w0.z + g3 * w0.w;
    s1 += g0 * w1.x + g1 * w1.y + g2 * w1.z + g3 * w1.w;
  }
  out[ro + lane] = s0;
  out[ro + lane + 64] = s1;
}

// ---------------------------------------------------------------------------
// K10: in-place per-128-row-tile SGEMM: out = relu(out @ W_lin^T + b_lin).
// __launch_bounds__(256,3) + rolled kq-loop + one-b-at-a-time keeps VGPR low
// (R7 failure: 256 VGPR, 8.8% occupancy).
__global__ __launch_bounds__(256, 3) void gemm2_kernel(
    const float* __restrict__ W_lin, const float* __restrict__ b_lin,
    float* __restrict__ out) {
  __shared__ __align__(16) float xs[128 * 32];
  __shared__ __align__(16) float wl[128 * 32];
  int t = threadIdx.x;
  int tn = t & 15, tm = t >> 4;
  int m0 = 4 * tm, n0 = 4 * tn;
  int vbase = blockIdx.x * 128;
  float acc[8][8] = {};

  for (int ks = 0; ks < D; ks += 32) {
    __syncthreads();
#pragma unroll
    for (int i = 0; i < 4; ++i) {
      int f = t + i * 256;
      int r = f >> 3, kq = f & 7;
      int sw = (4 * kq) ^ (4 * ((r >> 2) & 7));
      float4 xv = make_float4(0.f, 0.f, 0.f, 0.f);
      if (vbase + r < N_NODES)
        xv = *(const float4*)&out[(size_t)(vbase + r) * D + ks + 4 * kq];
      *(float4*)&xs[r * 32 + sw] = xv;
      *(float4*)&wl[r * 32 + sw] = *(const float4*)&W_lin[r * D + ks + 4 * kq];
    }
    __syncthreads();
#pragma unroll 1
    for (int kq = 0; kq < 8; ++kq) {
      int sa = (4 * kq) ^ (4 * (tm & 7));
      int sb = (4 * kq) ^ (4 * (tn & 7));
      float4 a[8];
#pragma unroll
      for (int i = 0; i < 4; ++i) {
        a[i] = *(const float4*)&xs[(m0 + i) * 32 + sa];
        a[4 + i] = *(const float4*)&xs[(m0 + 64 + i) * 32 + sa];
      }
#pragma unroll
      for (int j = 0; j < 8; ++j) {
        int rj = (j < 4) ? (n0 + j) : (n0 + 60 + j);
        float4 b = *(const float4*)&wl[rj * 32 + sb];
#pragma unroll
        for (int i = 0; i < 8; ++i) {
          acc[i][j] += a[i].x * b.x + a[i].y * b.y + a[i].z * b.z +
                       a[i].w * b.w;
        }
      }
    }
  }

  float bl[8];
#pragma unroll
  for (int j = 0; j < 4; ++j) {
    bl[j] = b_lin[n0 + j];
    bl[4 + j] = b_lin[n0 + 64 + j];
  }
#pragma unroll
  for (int i = 0; i < 8; ++i) {
    int m = vbase + m0 + (i < 4 ? i : 64 + i - 4);
    if (m >= N_NODES) continue;
    float4 o0, o1;
    o0.x = fmaxf(acc[i][0] + bl[0], 0.f);
    o0.y = fmaxf(acc[i][1] + bl[1], 0.f);
    o0.z = fmaxf(acc[i][2] + bl[2], 0.f);
    o0.w = fmaxf(acc[i][3] + bl[3], 0.f);
    o1.x = fmaxf(acc[i][4] + bl[4], 0.f);
    o1.y = fmaxf(acc[i][5] + bl[5], 0.f);
    o1.z = fmaxf(acc[i][6] + bl[6], 0.f);
    o1.w = fmaxf(acc[i][7] + bl[7], 0.f);
    *(float4*)&out[(size_t)m * D + n0] = o0;
    *(float4*)&out[(size_t)m * D + n0 + 64] = o1;
  }
}

// ---------------------------------------------------------------------------
extern "C" void kernel_launch(void* const* d_in, const int* in_sizes, int n_in,
                              void* d_out, int out_size, void* d_ws,
                              size_t ws_size, hipStream_t stream) {
  const float* x      = (const float*)d_in[0];
  const int*   el     = (const int*)d_in[1];
  const float* ew     = (const float*)d_in[2];
  const float* ef     = (const float*)d_in[3];
  const float* W_lin  = (const float*)d_in[4];
  const float* b_lin  = (const float*)d_in[5];
  const float* W_edge = (const float*)d_in[6];
  const float* b_edge = (const float*)d_in[7];

  float* outp = (float*)d_out;

  // workspace layout (~61.3 MB); xh aliases rec (dead after gather_ef, equal size)
  char* base = (char*)d_ws;
  size_t off = 0;
  int4* rec      = (int4*)(base + off); off += (size_t)N_EDGES * 16;
  int2* recSW    = (int2*)(base + off); off += (size_t)N_EDGES * 8;
  int*  pos      = (int*)(base + off);  off += (size_t)N_EDGES * 4;
  float* deg4    = (float*)(base + off); off += (size_t)4 * N_NODES * 4;
  int*  cursor   = (int*)(base + off);  off += (size_t)N_NODES * 4;
  int*  partial  = (int*)(base + off);  off += (size_t)N_NODES * 4;
  int*  blocksum = (int*)(base + off);  off += 512;
  int*  blockoff = (int*)(base + off);  off += 512;
  float* rdi     = (float*)(base + off); off += (size_t)N_NODES * 4;
  float* rdo     = (float*)(base + off); off += (size_t)N_NODES * 4;
  float* wsum    = (float*)(base + off); off += (size_t)N_NODES * 4;
  float* g       = (float*)(base + off); off += (size_t)N_NODES * DE * 4;
  const size_t REQ_FAST = off;
  bool fast = (ws_size >= REQ_FAST);
  if (!fast) {
    // fallback layout: drop recSW, shift everything after it down 12.8MB
    off = (size_t)N_EDGES * 16;
    pos      = (int*)(base + off);  off += (size_t)N_EDGES * 4;
    deg4     = (float*)(base + off); off += (size_t)4 * N_NODES * 4;
    cursor   = (int*)(base + off);  off += (size_t)N_NODES * 4;
    partial  = (int*)(base + off);  off += (size_t)N_NODES * 4;
    blocksum = (int*)(base + off);  off += 512;
    blockoff = (int*)(base + off);  off += 512;
    rdi      = (float*)(base + off); off += (size_t)N_NODES * 4;
    rdo      = (float*)(base + off); off += (size_t)N_NODES * 4;
    wsum     = (float*)(base + off); off += (size_t)N_NODES * 4;
    g        = (float*)(base + off); off += (size_t)N_NODES * DE * 4;
  }
  ushort* xh = (ushort*)rec;  // alias, valid only after gather_ef (fast path)

  hipLaunchKernelGGL(init_kernel, dim3((5 * N_NODES + 255) / 256), dim3(256),
                     0, stream, (int*)deg4);
  hipLaunchKernelGGL(pos_kernel, dim3((N_EDGES / 2 + 255) / 256), dim3(256), 0,
                     stream, (const int4*)el, cursor, (int2*)pos);
  hipLaunchKernelGGL(scan1_kernel, dim3(N_CHUNKS), dim3(256), 0, stream,
                     cursor, partial, blocksum);
  hipLaunchKernelGGL(scan2_kernel, dim3(1), dim3(128), 0, stream, blocksum,
                     blockoff);
  hipLaunchKernelGGL(place_kernel, dim3((N_EDGES / 2 + 255) / 256), dim3(256),
                     0, stream, (const int4*)el, (const float2*)ew,
                     (const int2*)pos, partial, blockoff, deg4, rec);
  hipLaunchKernelGGL(rdi_kernel, dim3((N_NODES + 255) / 256), dim3(256), 0,
                     stream, deg4, rdi);
  if (fast) {
    hipLaunchKernelGGL(wpre_kernel, dim3((N_EDGES + 255) / 256), dim3(256), 0,
                       stream, (const int4*)rec, rdi, recSW);
  }
  hipLaunchKernelGGL(gather_ef_kernel, dim3((N_NODES + 3) / 4), dim3(256), 0,
                     stream, ef, partial, blockoff, cursor, rec, rdi, g, wsum,
                     rdo);
  if (fast) {
    hipLaunchKernelGGL(xh_kernel, dim3((N_NODES * D / 8 + 255) / 256),
                       dim3(256), 0, stream, (const float4*)x, (uint4*)xh);
    hipLaunchKernelGGL(gather_x_fast_kernel, dim3((N_NODES + 3) / 4),
                       dim3(256), 0, stream, xh, partial, blockoff, cursor,
                       (const int2*)recSW, rdi, g, wsum, rdo, W_edge, b_edge,
                       outp);
  } else {
    hipLaunchKernelGGL(gather_x_safe_kernel, dim3((N_NODES + 3) / 4),
                       dim3(256), 0, stream, x, partial, blockoff, cursor, rec,
                       rdi, g, wsum, rdo, W_edge, b_edge, outp);
  }
  hipLaunchKernelGGL(gemm2_kernel, dim3((N_NODES + 127) / 128), dim3(256), 0,
                     stream, W_lin, b_lin, outp);
}

// Round 10
// 390.959 us; speedup vs baseline: 1.4300x; 1.1626x over previous
//
#include <hip/hip_runtime.h>

#define N_NODES 100000
#define N_EDGES 1600000
#define D 128
#define DE 32
#define SCAN_CHUNK 1024
#define N_CHUNKS ((N_NODES + SCAN_CHUNK - 1) / SCAN_CHUNK)  // 98

// NOTE on eps: reference divides by sqrt(deg_in*deg_out)+1e-10 with both
// degrees >= 1, so the +1e-10 is a 1e-10 relative perturbation — far below
// f32 rounding. We factor w = ew * rsqrt(di) * rsqrt(do), and since rdo is
// uniform per dst-node, the whole row is accumulated with w' = ew*rdi[src]
// and scaled by rdo once at the end.
//
// NOTE on bf16 gather (R9): neighbor-sum reads bf16(x) (RNE) with f32
// accumulation. Added output error well under the 0.019 threshold (measured
// absmax 0.0039, unchanged from f32).

__device__ inline float bfu(ushort u) {
  return __uint_as_float((unsigned)u << 16);
}
__device__ inline unsigned pk_bf2(float lo, float hi) {
  unsigned a = __float_as_uint(lo), b = __float_as_uint(hi);
  a = (a + 0x7FFFu + ((a >> 16) & 1)) >> 16;  // RNE
  b = (b + 0x7FFFu + ((b >> 16) & 1)) >> 16;
  return a | (b << 16);
}

// ---------------------------------------------------------------------------
// K1: zero deg replicas + cursor (contiguous 5N region).
__global__ __launch_bounds__(256) void init_kernel(int* __restrict__ z) {
  int idx = blockIdx.x * 256 + threadIdx.x;
  if (idx < 5 * N_NODES) z[idx] = 0;
}

// ---------------------------------------------------------------------------
// K2: per-edge cursor position atomic ONLY (1.6M atomics). 2 edges/thread.
__global__ __launch_bounds__(256) void pos_kernel(
    const int4* __restrict__ el2, int* __restrict__ cursor,
    int2* __restrict__ pos2) {
  int i = blockIdx.x * 256 + threadIdx.x;  // edge-pair index
  if (i >= N_EDGES / 2) return;
  int4 e = el2[i];
  int2 p;
  p.x = atomicAdd(&cursor[e.y], 1);
  p.y = atomicAdd(&cursor[e.w], 1);
  pos2[i] = p;
}

// ---------------------------------------------------------------------------
// K3a: per-1024-chunk exclusive scan of counts(=cursor) -> partial, totals.
__global__ __launch_bounds__(256) void scan1_kernel(
    const int* __restrict__ counts, int* __restrict__ partial,
    int* __restrict__ blocksum) {
  __shared__ int lds[256];
  int t = threadIdx.x;
  int base = blockIdx.x * SCAN_CHUNK + t * 4;
  int c[4];
  int s = 0;
#pragma unroll
  for (int k = 0; k < 4; k++) {
    c[k] = (base + k < N_NODES) ? counts[base + k] : 0;
    s += c[k];
  }
  lds[t] = s;
  __syncthreads();
  for (int off = 1; off < 256; off <<= 1) {
    int tmp = (t >= off) ? lds[t - off] : 0;
    __syncthreads();
    lds[t] += tmp;
    __syncthreads();
  }
  int run = lds[t] - s;
#pragma unroll
  for (int k = 0; k < 4; k++) {
    int v = base + k;
    if (v < N_NODES) partial[v] = run;
    run += c[k];
  }
  if (t == 255) blocksum[blockIdx.x] = lds[255];
}

// ---------------------------------------------------------------------------
// K3b: exclusive scan of the 98 chunk totals.
__global__ __launch_bounds__(128) void scan2_kernel(
    const int* __restrict__ blocksum, int* __restrict__ blockoff) {
  __shared__ int lds[128];
  int t = threadIdx.x;
  int v = (t < N_CHUNKS) ? blocksum[t] : 0;
  lds[t] = v;
  __syncthreads();
  for (int off = 1; off < 128; off <<= 1) {
    int tmp = (t >= off) ? lds[t - off] : 0;
    __syncthreads();
    lds[t] += tmp;
    __syncthreads();
  }
  if (t < N_CHUNKS) blockoff[t] = lds[t] - v;
}

// ---------------------------------------------------------------------------
// K4: place 16B AoS records {src, eid, ew, 0} at start[dst]+pos + deg_in
// replica atomics.
__global__ __launch_bounds__(256) void place_kernel(
    const int4* __restrict__ el2, const float2* __restrict__ ew2,
    const int2* __restrict__ pos2, const int* __restrict__ partial,
    const int* __restrict__ blockoff, float* __restrict__ deg4,
    int4* __restrict__ rec) {
  int i = blockIdx.x * 256 + threadIdx.x;  // edge-pair index
  if (i >= N_EDGES / 2) return;
  int4 e = el2[i];
  float2 w = ew2[i];
  int2 p = pos2[i];
  int r0 = (threadIdx.x & 3) * N_NODES;
  atomicAdd(&deg4[r0 + e.x], w.x);
  atomicAdd(&deg4[r0 + e.z], w.y);
  int4 rA, rB;
  rA.x = e.x; rA.y = 2 * i;     rA.z = __float_as_int(w.x); rA.w = 0;
  rB.x = e.z; rB.y = 2 * i + 1; rB.z = __float_as_int(w.y); rB.w = 0;
  rec[partial[e.y] + blockoff[e.y >> 10] + p.x] = rA;
  rec[partial[e.w] + blockoff[e.w >> 10] + p.y] = rB;
}

// ---------------------------------------------------------------------------
// K5: finalize rdi = rsqrt(1 + sum of 4 deg replicas).
__global__ __launch_bounds__(256) void rdi_kernel(
    const float* __restrict__ deg4, float* __restrict__ rdi) {
  int v = blockIdx.x * 256 + threadIdx.x;
  if (v >= N_NODES) return;
  rdi[v] = rsqrtf(1.f + deg4[v] + deg4[N_NODES + v] + deg4[2 * N_NODES + v] +
                  deg4[3 * N_NODES + v]);
}

// ---------------------------------------------------------------------------
// K6: xh = bf16(x) table (RNE), 8 elems/thread.
__global__ __launch_bounds__(256) void xh_kernel(
    const float4* __restrict__ x4, uint4* __restrict__ xh4) {
  int i = blockIdx.x * 256 + threadIdx.x;
  if (i >= N_NODES * D / 8) return;
  float4 f0 = x4[2 * i], f1 = x4[2 * i + 1];
  uint4 o;
  o.x = pk_bf2(f0.x, f0.y);
  o.y = pk_bf2(f0.z, f0.w);
  o.z = pk_bf2(f1.x, f1.y);
  o.w = pk_bf2(f1.z, f1.w);
  xh4[i] = o;
}

// ---------------------------------------------------------------------------
// K7: single-pass fused gather (ef + x + row epilogue). One wave per node.
// Everything accumulated with w' = ew*rdi[src]; rdo applied once at the end.
// g never materializes (stays in registers, feeds the W_edge epilogue);
// dsum (raw ew sum -> rdo) folds into the batch load; no second CSR pass.
// ef reads are nt-hinted (zero reuse); xh (25.6MB bf16, 16x avg reuse)
// stays L3-warm.
template <bool BF16>
__global__ __launch_bounds__(256) void gather_fused_kernel(
    const float* __restrict__ x, const ushort* __restrict__ xh,
    const float* __restrict__ ef, const int* __restrict__ partial,
    const int* __restrict__ blockoff, const int* __restrict__ counts,
    const int4* __restrict__ rec, const float* __restrict__ rdi,
    const float* __restrict__ W_edge, const float* __restrict__ b_edge,
    float* __restrict__ out) {
  __shared__ __align__(16) float we[128 * 36];
  __shared__ float beS[128];
  int t = threadIdx.x;
#pragma unroll
  for (int i = 0; i < 4; ++i) {  // 1024 float4 / 256 threads
    int f = t + i * 256;
    int r = f >> 3, kq = f & 7;
    *(float4*)&we[r * 36 + 4 * kq] = *(const float4*)&W_edge[r * DE + 4 * kq];
  }
  if (t < 128) beS[t] = b_edge[t];
  __syncthreads();

  int wid = t >> 6, lane = t & 63;
  int v = blockIdx.x * 4 + wid;
  if (v >= N_NODES) return;
  int start = partial[v] + blockoff[v >> 10];
  int cnt = counts[v];

  float A0 = 0.f, A1 = 0.f, B0 = 0.f, B1 = 0.f;
  float C0 = 0.f, C1 = 0.f, E0 = 0.f, E1 = 0.f;
  float ga = 0.f, gb = 0.f, dsum = 0.f, wsv = 0.f;

  for (int base = 0; base < cnt; base += 64) {
    int nb = cnt - base;
    if (nb > 64) nb = 64;
    int s_l = 0, e_l = 0;
    float w_l = 0.f;
    if (lane < nb) {
      int4 r = rec[start + base + lane];
      s_l = r.x;
      e_l = r.y;
      float wraw = __int_as_float(r.z);
      w_l = wraw * rdi[r.x];
      dsum += wraw;  // pass-1 folded in
      wsv += w_l;
    }
    int i = 0;
    for (; i + 4 <= nb; i += 4) {
      int s0 = __shfl(s_l, i), s1 = __shfl(s_l, i + 1);
      int s2 = __shfl(s_l, i + 2), s3 = __shfl(s_l, i + 3);
      float w0 = __shfl(w_l, i), w1 = __shfl(w_l, i + 1);
      float w2 = __shfl(w_l, i + 2), w3 = __shfl(w_l, i + 3);
      // ef: two half-wave pairs
      int selA = i + (lane >> 5), selB = i + 2 + (lane >> 5);
      int eA = __shfl(e_l, selA), eB = __shfl(e_l, selB);
      float wA = __shfl(w_l, selA), wB = __shfl(w_l, selB);
      ga = fmaf(wA,
                __builtin_nontemporal_load(&ef[(size_t)eA * DE + (lane & 31)]),
                ga);
      gb = fmaf(wB,
                __builtin_nontemporal_load(&ef[(size_t)eB * DE + (lane & 31)]),
                gb);
      // x: four full-wave rows
      if (BF16) {
        const ushort* p0 = xh + (size_t)s0 * D;
        const ushort* p1 = xh + (size_t)s1 * D;
        const ushort* p2 = xh + (size_t)s2 * D;
        const ushort* p3 = xh + (size_t)s3 * D;
        A0 = fmaf(w0, bfu(p0[lane]), A0);
        A1 = fmaf(w0, bfu(p0[lane + 64]), A1);
        B0 = fmaf(w1, bfu(p1[lane]), B0);
        B1 = fmaf(w1, bfu(p1[lane + 64]), B1);
        C0 = fmaf(w2, bfu(p2[lane]), C0);
        C1 = fmaf(w2, bfu(p2[lane + 64]), C1);
        E0 = fmaf(w3, bfu(p3[lane]), E0);
        E1 = fmaf(w3, bfu(p3[lane + 64]), E1);
      } else {
        const float* p0 = x + (size_t)s0 * D;
        const float* p1 = x + (size_t)s1 * D;
        const float* p2 = x + (size_t)s2 * D;
        const float* p3 = x + (size_t)s3 * D;
        A0 = fmaf(w0, p0[lane], A0);
        A1 = fmaf(w0, p0[lane + 64], A1);
        B0 = fmaf(w1, p1[lane], B0);
        B1 = fmaf(w1, p1[lane + 64], B1);
        C0 = fmaf(w2, p2[lane], C0);
        C1 = fmaf(w2, p2[lane + 64], C1);
        E0 = fmaf(w3, p3[lane], E0);
        E1 = fmaf(w3, p3[lane + 64], E1);
      }
    }
    for (; i + 2 <= nb; i += 2) {
      int s0 = __shfl(s_l, i), s1 = __shfl(s_l, i + 1);
      float w0 = __shfl(w_l, i), w1 = __shfl(w_l, i + 1);
      int sel = i + (lane >> 5);
      int eE = __shfl(e_l, sel);
      float wE = __shfl(w_l, sel);
      ga = fmaf(wE,
                __builtin_nontemporal_load(&ef[(size_t)eE * DE + (lane & 31)]),
                ga);
      if (BF16) {
        const ushort* p0 = xh + (size_t)s0 * D;
        const ushort* p1 = xh + (size_t)s1 * D;
        A0 = fmaf(w0, bfu(p0[lane]), A0);
        A1 = fmaf(w0, bfu(p0[lane + 64]), A1);
        B0 = fmaf(w1, bfu(p1[lane]), B0);
        B1 = fmaf(w1, bfu(p1[lane + 64]), B1);
      } else {
        const float* p0 = x + (size_t)s0 * D;
        const float* p1 = x + (size_t)s1 * D;
        A0 = fmaf(w0, p0[lane], A0);
        A1 = fmaf(w0, p0[lane + 64], A1);
        B0 = fmaf(w1, p1[lane], B0);
        B1 = fmaf(w1, p1[lane + 64], B1);
      }
    }
    if (i < nb) {
      int s0 = __shfl(s_l, i);
      float w0 = __shfl(w_l, i);
      int eA = __shfl(e_l, i);
      if (lane < DE)
        ga = fmaf(w0, __builtin_nontemporal_load(&ef[(size_t)eA * DE + lane]),
                  ga);
      if (BF16) {
        const ushort* p0 = xh + (size_t)s0 * D;
        A0 = fmaf(w0, bfu(p0[lane]), A0);
        A1 = fmaf(w0, bfu(p0[lane + 64]), A1);
      } else {
        const float* p0 = x + (size_t)s0 * D;
        A0 = fmaf(w0, p0[lane], A0);
        A1 = fmaf(w0, p0[lane + 64], A1);
      }
    }
  }
  float a0 = (A0 + B0) + (C0 + E0);
  float a1 = (A1 + B1) + (C1 + E1);
#pragma unroll
  for (int off = 32; off; off >>= 1) {
    dsum += __shfl_xor(dsum, off);
    wsv += __shfl_xor(wsv, off);
  }
  float rdo = rsqrtf(1.f + dsum);
  float gk = ga + gb;
  gk = gk + __shfl(gk, (lane + 32) & 63);  // lanes 0..31 hold full g_k

  // epilogue (all terms pre-rdo; one scale at the end)
  size_t ro = (size_t)v * D;
  float xs0, xs1;
  if (BF16) {
    xs0 = bfu(xh[ro + lane]);
    xs1 = bfu(xh[ro + lane + 64]);
  } else {
    xs0 = x[ro + lane];
    xs1 = x[ro + lane + 64];
  }
  float wselfp = rdi[v];
  float s0 = a0 + wselfp * xs0 + wsv * beS[lane];
  float s1 = a1 + wselfp * xs1 + wsv * beS[lane + 64];
#pragma unroll
  for (int kq = 0; kq < 8; ++kq) {
    float4 w0 = *(const float4*)&we[lane * 36 + 4 * kq];
    float4 w1 = *(const float4*)&we[(lane + 64) * 36 + 4 * kq];
    float g0 = __shfl(gk, 4 * kq);
    float g1 = __shfl(gk, 4 * kq + 1);
    float g2 = __shfl(gk, 4 * kq + 2);
    float g3 = __shfl(gk, 4 * kq + 3);
    s0 += g0 * w0.x + g1 * w0.y + g2 * w0.z + g3 * w0.w;
    s1 += g0 * w1.x + g1 * w1.y + g2 * w1.z + g3 * w1.w;
  }
  out[ro + lane] = rdo * s0;
  out[ro + lane + 64] = rdo * s1;
}

// ---------------------------------------------------------------------------
// K8: in-place per-128-row-tile SGEMM: out = relu(out @ W_lin^T + b_lin).
// __launch_bounds__(256,3) + rolled kq-loop + one-b-at-a-time keeps VGPR low
// (R7 failure: 256 VGPR, 8.8% occupancy).
__global__ __launch_bounds__(256, 3) void gemm2_kernel(
    const float* __restrict__ W_lin, const float* __restrict__ b_lin,
    float* __restrict__ out) {
  __shared__ __align__(16) float xs[128 * 32];
  __shared__ __align__(16) float wl[128 * 32];
  int t = threadIdx.x;
  int tn = t & 15, tm = t >> 4;
  int m0 = 4 * tm, n0 = 4 * tn;
  int vbase = blockIdx.x * 128;
  float acc[8][8] = {};

  for (int ks = 0; ks < D; ks += 32) {
    __syncthreads();
#pragma unroll
    for (int i = 0; i < 4; ++i) {
      int f = t + i * 256;
      int r = f >> 3, kq = f & 7;
      int sw = (4 * kq) ^ (4 * ((r >> 2) & 7));
      float4 xv = make_float4(0.f, 0.f, 0.f, 0.f);
      if (vbase + r < N_NODES)
        xv = *(const float4*)&out[(size_t)(vbase + r) * D + ks + 4 * kq];
      *(float4*)&xs[r * 32 + sw] = xv;
      *(float4*)&wl[r * 32 + sw] = *(const float4*)&W_lin[r * D + ks + 4 * kq];
    }
    __syncthreads();
#pragma unroll 1
    for (int kq = 0; kq < 8; ++kq) {
      int sa = (4 * kq) ^ (4 * (tm & 7));
      int sb = (4 * kq) ^ (4 * (tn & 7));
      float4 a[8];
#pragma unroll
      for (int i = 0; i < 4; ++i) {
        a[i] = *(const float4*)&xs[(m0 + i) * 32 + sa];
        a[4 + i] = *(const float4*)&xs[(m0 + 64 + i) * 32 + sa];
      }
#pragma unroll
      for (int j = 0; j < 8; ++j) {
        int rj = (j < 4) ? (n0 + j) : (n0 + 60 + j);
        float4 b = *(const float4*)&wl[rj * 32 + sb];
#pragma unroll
        for (int i = 0; i < 8; ++i) {
          acc[i][j] += a[i].x * b.x + a[i].y * b.y + a[i].z * b.z +
                       a[i].w * b.w;
        }
      }
    }
  }

  float bl[8];
#pragma unroll
  for (int j = 0; j < 4; ++j) {
    bl[j] = b_lin[n0 + j];
    bl[4 + j] = b_lin[n0 + 64 + j];
  }
#pragma unroll
  for (int i = 0; i < 8; ++i) {
    int m = vbase + m0 + (i < 4 ? i : 64 + i - 4);
    if (m >= N_NODES) continue;
    float4 o0, o1;
    o0.x = fmaxf(acc[i][0] + bl[0], 0.f);
    o0.y = fmaxf(acc[i][1] + bl[1], 0.f);
    o0.z = fmaxf(acc[i][2] + bl[2], 0.f);
    o0.w = fmaxf(acc[i][3] + bl[3], 0.f);
    o1.x = fmaxf(acc[i][4] + bl[4], 0.f);
    o1.y = fmaxf(acc[i][5] + bl[5], 0.f);
    o1.z = fmaxf(acc[i][6] + bl[6], 0.f);
    o1.w = fmaxf(acc[i][7] + bl[7], 0.f);
    *(float4*)&out[(size_t)m * D + n0] = o0;
    *(float4*)&out[(size_t)m * D + n0 + 64] = o1;
  }
}

// ---------------------------------------------------------------------------
extern "C" void kernel_launch(void* const* d_in, const int* in_sizes, int n_in,
                              void* d_out, int out_size, void* d_ws,
                              size_t ws_size, hipStream_t stream) {
  const float* x      = (const float*)d_in[0];
  const int*   el     = (const int*)d_in[1];
  const float* ew     = (const float*)d_in[2];
  const float* ef     = (const float*)d_in[3];
  const float* W_lin  = (const float*)d_in[4];
  const float* b_lin  = (const float*)d_in[5];
  const float* W_edge = (const float*)d_in[6];
  const float* b_edge = (const float*)d_in[7];

  float* outp = (float*)d_out;  // fused gather writes rows; gemm2 in place

  // workspace layout (~60.4 MB with xh; fallback ~34.8 MB without)
  char* base = (char*)d_ws;
  size_t off = 0;
  int4* rec      = (int4*)(base + off); off += (size_t)N_EDGES * 16;
  ushort* xh     = (ushort*)(base + off); off += (size_t)N_NODES * D * 2;
  int*  pos      = (int*)(base + off);  off += (size_t)N_EDGES * 4;
  float* deg4    = (float*)(base + off); off += (size_t)4 * N_NODES * 4;
  int*  cursor   = (int*)(base + off);  off += (size_t)N_NODES * 4;
  int*  partial  = (int*)(base + off);  off += (size_t)N_NODES * 4;
  int*  blocksum = (int*)(base + off);  off += 512;
  int*  blockoff = (int*)(base + off);  off += 512;
  float* rdi     = (float*)(base + off); off += (size_t)N_NODES * 4;
  const size_t REQ_FAST = off;
  bool fast = (ws_size >= REQ_FAST);
  if (!fast) {
    // fallback layout: drop xh, shift everything after it down 25.6MB
    off = (size_t)N_EDGES * 16;
    pos      = (int*)(base + off);  off += (size_t)N_EDGES * 4;
    deg4     = (float*)(base + off); off += (size_t)4 * N_NODES * 4;
    cursor   = (int*)(base + off);  off += (size_t)N_NODES * 4;
    partial  = (int*)(base + off);  off += (size_t)N_NODES * 4;
    blocksum = (int*)(base + off);  off += 512;
    blockoff = (int*)(base + off);  off += 512;
    rdi      = (float*)(base + off); off += (size_t)N_NODES * 4;
    xh       = nullptr;
  }

  hipLaunchKernelGGL(init_kernel, dim3((5 * N_NODES + 255) / 256), dim3(256),
                     0, stream, (int*)deg4);
  hipLaunchKernelGGL(pos_kernel, dim3((N_EDGES / 2 + 255) / 256), dim3(256), 0,
                     stream, (const int4*)el, cursor, (int2*)pos);
  hipLaunchKernelGGL(scan1_kernel, dim3(N_CHUNKS), dim3(256), 0, stream,
                     cursor, partial, blocksum);
  hipLaunchKernelGGL(scan2_kernel, dim3(1), dim3(128), 0, stream, blocksum,
                     blockoff);
  hipLaunchKernelGGL(place_kernel, dim3((N_EDGES / 2 + 255) / 256), dim3(256),
                     0, stream, (const int4*)el, (const float2*)ew,
                     (const int2*)pos, partial, blockoff, deg4, rec);
  hipLaunchKernelGGL(rdi_kernel, dim3((N_NODES + 255) / 256), dim3(256), 0,
                     stream, deg4, rdi);
  if (fast) {
    hipLaunchKernelGGL(xh_kernel, dim3((N_NODES * D / 8 + 255) / 256),
                       dim3(256), 0, stream, (const float4*)x, (uint4*)xh);
    hipLaunchKernelGGL(gather_fused_kernel<true>, dim3((N_NODES + 3) / 4),
                       dim3(256), 0, stream, x, xh, ef, partial, blockoff,
                       cursor, rec, rdi, W_edge, b_edge, outp);
  } else {
    hipLaunchKernelGGL(gather_fused_kernel<false>, dim3((N_NODES + 3) / 4),
                       dim3(256), 0, stream, x, xh, ef, partial, blockoff,
                       cursor, rec, rdi, W_edge, b_edge, outp);
  }
  hipLaunchKernelGGL(gemm2_kernel, dim3((N_NODES + 127) / 128), dim3(256), 0,
                     stream, W_lin, b_lin, outp);
}